// Round 6
// baseline (1433.439 us; speedup 1.0000x reference)
//
#include <hip/hip_runtime.h>
#include <hip/hip_bf16.h>

typedef __attribute__((ext_vector_type(8))) short bf16x8;
typedef __attribute__((ext_vector_type(4))) float f32x4;
typedef unsigned short u16;
typedef __attribute__((ext_vector_type(4))) unsigned short u16x4;

#define L_ 4
#define E_ 1024
#define H_ 16
#define F_ 4096
#define B_ 8
#define S_ 512
#define T_ 4096
#define GEN_N 1200

static __device__ __forceinline__ u16 f2bf(float f) {
  unsigned u = __float_as_uint(f);
  unsigned r = (u + 0x7fffu + ((u >> 16) & 1u)) >> 16;
  return (u16)r;
}

static __device__ __forceinline__ float fast_gelu(float v) {
  float y = 0.7978845608f * (v + 0.044715f * v * v * v);
  y = fminf(fmaxf(y, -9.f), 9.f);
  float e2 = __expf(2.f * y);
  float th = (e2 - 1.f) / (e2 + 1.f);
  return 0.5f * v * (1.f + th);
}

// ---------------- f32 -> bf16 convert ----------------
__global__ __launch_bounds__(256) void cvt_bf16(const float* __restrict__ src,
                                                u16* __restrict__ dst, int n) {
  int i = (blockIdx.x * 256 + threadIdx.x) * 4;
  if (i >= n) return;
  float4 v = *reinterpret_cast<const float4*>(src + i);
  u16x4 o = {f2bf(v.x), f2bf(v.y), f2bf(v.z), f2bf(v.w)};
  *reinterpret_cast<u16x4*>(dst + i) = o;
}

// ---------------- embedding ----------------
__global__ __launch_bounds__(256) void embed_k(const float* __restrict__ val_emb,
                                               const float* __restrict__ ring_emb,
                                               const int* __restrict__ vseq,
                                               const int* __restrict__ rseq,
                                               float* __restrict__ h, u16* __restrict__ xbf) {
  int tok = blockIdx.x;
  int e = threadIdx.x * 4;
  int v = vseq[tok], r = rseq[tok];
  float4 a = *reinterpret_cast<const float4*>(val_emb + v * E_ + e);
  float4 b = *reinterpret_cast<const float4*>(ring_emb + r * E_ + e);
  float4 o;
  o.x = (a.x + b.x) * 32.f; o.y = (a.y + b.y) * 32.f;
  o.z = (a.z + b.z) * 32.f; o.w = (a.w + b.w) * 32.f;
  *reinterpret_cast<float4*>(h + (size_t)tok * E_ + e) = o;
  u16x4 ob = {f2bf(o.x), f2bf(o.y), f2bf(o.z), f2bf(o.w)};
  *reinterpret_cast<u16x4*>(xbf + (size_t)tok * E_ + e) = ob;
}

// ---------------- LayerNorm ----------------
__global__ __launch_bounds__(256) void ln_k(const float* hin,
                                            const float* g, const float* bta,
                                            float* hout, u16* xout) {
  int tok = blockIdx.x;
  int e = threadIdx.x * 4;
  float4 v = *reinterpret_cast<const float4*>(hin + (size_t)tok * E_ + e);
  float s = v.x + v.y + v.z + v.w;
  float q = v.x * v.x + v.y * v.y + v.z * v.z + v.w * v.w;
  #pragma unroll
  for (int off = 1; off < 64; off <<= 1) {
    s += __shfl_xor(s, off, 64);
    q += __shfl_xor(q, off, 64);
  }
  __shared__ float ls[4], lq[4];
  int wv = threadIdx.x >> 6, ln = threadIdx.x & 63;
  if (ln == 0) { ls[wv] = s; lq[wv] = q; }
  __syncthreads();
  s = ls[0] + ls[1] + ls[2] + ls[3];
  q = lq[0] + lq[1] + lq[2] + lq[3];
  float mean = s * (1.f / E_);
  float var = q * (1.f / E_) - mean * mean;
  float inv = rsqrtf(var + 1e-5f);
  float4 gg = *reinterpret_cast<const float4*>(g + e);
  float4 bb = *reinterpret_cast<const float4*>(bta + e);
  float4 o;
  o.x = (v.x - mean) * inv * gg.x + bb.x;
  o.y = (v.y - mean) * inv * gg.y + bb.y;
  o.z = (v.z - mean) * inv * gg.z + bb.z;
  o.w = (v.w - mean) * inv * gg.w + bb.w;
  if (hout) *reinterpret_cast<float4*>(hout + (size_t)tok * E_ + e) = o;
  u16x4 ob = {f2bf(o.x), f2bf(o.y), f2bf(o.z), f2bf(o.w)};
  *reinterpret_cast<u16x4*>(xout + (size_t)tok * E_ + e) = ob;
}

// ---------------- GEMM: C[M,N] = A[M,K] @ W[N,K]^T + bias ----------------
// Double-buffered LDS + counted vmcnt across raw s_barrier (T4): prefetch of
// tile t+1 stays in flight through the barrier; no vmcnt(0) drain in the loop.
// XOR k-chunk swizzle (T2): global source chunk ^(row&3), linear LDS dest,
// read chunk lk^(lr&3) -> bank-conflict-free ds_read_b128.
// EPI: 0 = bf16 out, 1 = gelu -> bf16 out, 2 = f32 out, 3 = f32 accumulate
template <int EPI>
__global__ __launch_bounds__(256) void gemm_bt(const u16* __restrict__ A,
                                               const u16* __restrict__ W,
                                               const float* __restrict__ bias,
                                               void* __restrict__ Cp,
                                               int M, int N, int K, int tilesN) {
  __shared__ __align__(16) u16 As[2][128 * 32];
  __shared__ __align__(16) u16 Bs[2][128 * 32];
  int tid = threadIdx.x;
  int wv = tid >> 6, ln = tid & 63;
  int wm = wv >> 1, wn = wv & 1;
  int nwg = gridDim.x;
  int bid = blockIdx.x;
  int swz = ((nwg & 7) == 0) ? ((bid & 7) * (nwg >> 3) + (bid >> 3)) : bid;
  int tm = swz / tilesN, tn = swz % tilesN;
  int row0 = tm * 128, col0 = tn * 128;
  int lr = ln & 15, lk = ln >> 4;

  f32x4 acc[4][4];
  f32x4 z = {0.f, 0.f, 0.f, 0.f};
  #pragma unroll
  for (int m = 0; m < 4; ++m)
    #pragma unroll
    for (int n = 0; n < 4; ++n) acc[m][n] = z;

  // staging coords: thread -> (row srow, k-chunk), source chunk XOR-swizzled
  int srow = tid >> 2;                              // 0..63
  int scol = ((tid & 3) ^ (srow & 3)) * 8;          // u16 offset of 16B chunk
  const u16* gA0 = A + (size_t)(row0 + srow) * K + scol;
  const u16* gA1 = A + (size_t)(row0 + 64 + srow) * K + scol;
  int wr0 = col0 + srow;      if (wr0 >= N) wr0 = N - 1;
  int wr1 = col0 + 64 + srow; if (wr1 >= N) wr1 = N - 1;
  const u16* gB0 = W + (size_t)wr0 * K + scol;
  const u16* gB1 = W + (size_t)wr1 * K + scol;
  size_t ldsOff0 = (size_t)(wv << 6) * 16;          // bytes, + lane*16 by HW
  size_t ldsOff1 = (size_t)(256 + (wv << 6)) * 16;

  auto stage = [&](int buf, int k0) {
    __builtin_amdgcn_global_load_lds(
        (const __attribute__((address_space(1))) void*)(gA0 + k0),
        (__attribute__((address_space(3))) void*)((char*)&As[buf][0] + ldsOff0), 16, 0, 0);
    __builtin_amdgcn_global_load_lds(
        (const __attribute__((address_space(1))) void*)(gB0 + k0),
        (__attribute__((address_space(3))) void*)((char*)&Bs[buf][0] + ldsOff0), 16, 0, 0);
    __builtin_amdgcn_global_load_lds(
        (const __attribute__((address_space(1))) void*)(gA1 + k0),
        (__attribute__((address_space(3))) void*)((char*)&As[buf][0] + ldsOff1), 16, 0, 0);
    __builtin_amdgcn_global_load_lds(
        (const __attribute__((address_space(1))) void*)(gB1 + k0),
        (__attribute__((address_space(3))) void*)((char*)&Bs[buf][0] + ldsOff1), 16, 0, 0);
  };

  int ck = (lk ^ (lr & 3)) * 8;  // read-side swizzled chunk (u16 units)
  auto compute = [&](int buf) {
    bf16x8 af[4], bfr[4];
    #pragma unroll
    for (int m = 0; m < 4; ++m)
      af[m] = *reinterpret_cast<const bf16x8*>(&As[buf][(wm * 64 + m * 16 + lr) * 32 + ck]);
    #pragma unroll
    for (int n = 0; n < 4; ++n)
      bfr[n] = *reinterpret_cast<const bf16x8*>(&Bs[buf][(wn * 64 + n * 16 + lr) * 32 + ck]);
    #pragma unroll
    for (int m = 0; m < 4; ++m)
      #pragma unroll
      for (int n = 0; n < 4; ++n)
        acc[m][n] = __builtin_amdgcn_mfma_f32_16x16x32_bf16(af[m], bfr[n], acc[m][n], 0, 0, 0);
  };

  int nsteps = K >> 5;
  stage(0, 0);
  for (int t = 0; t < nsteps - 1; ++t) {
    stage((t + 1) & 1, (t + 1) << 5);                  // prefetch next tile
    asm volatile("s_waitcnt vmcnt(4)" ::: "memory");   // my 4 loads of tile t done
    __builtin_amdgcn_s_barrier();                      // all waves' tile-t loads done
    asm volatile("" ::: "memory");
    compute(t & 1);
    asm volatile("" ::: "memory");
    __builtin_amdgcn_s_barrier();                      // readers done -> buf reusable
  }
  asm volatile("s_waitcnt vmcnt(0)" ::: "memory");
  __builtin_amdgcn_s_barrier();
  asm volatile("" ::: "memory");
  compute((nsteps - 1) & 1);

  #pragma unroll
  for (int n = 0; n < 4; ++n) {
    int col = col0 + wn * 64 + n * 16 + lr;
    if (col >= N) continue;
    float bv = bias[col];
    #pragma unroll
    for (int m = 0; m < 4; ++m) {
      int rbase = row0 + wm * 64 + m * 16 + lk * 4;
      #pragma unroll
      for (int r2 = 0; r2 < 4; ++r2) {
        float v = acc[m][n][r2] + bv;
        if (EPI == 1) v = fast_gelu(v);
        int row = rbase + r2;
        if (EPI == 2)
          ((float*)Cp)[(size_t)row * N + col] = v;
        else if (EPI == 3)
          ((float*)Cp)[(size_t)row * N + col] += v;
        else
          ((u16*)Cp)[(size_t)row * N + col] = f2bf(v);
      }
    }
  }
}

// ---------------- V transpose: Vt[bh][d][k] = V[bh][k][d] ----------------
__global__ __launch_bounds__(256) void vtrans_k(const u16* __restrict__ qkv,
                                                u16* __restrict__ Vt) {
  int blk = blockIdx.x;
  int kt = blk & 7, bh = blk >> 3;
  int b = bh >> 4, h = bh & 15;
  __shared__ u16 t[64 * 66];
  int tid = threadIdx.x;
  #pragma unroll
  for (int i = 0; i < 16; ++i) {
    int idx = i * 256 + tid;
    int kk = idx >> 6, d = idx & 63;
    t[kk * 66 + d] = qkv[(size_t)(b * S_ + kt * 64 + kk) * 3072 + 2 * E_ + h * 64 + d];
  }
  __syncthreads();
  #pragma unroll
  for (int i = 0; i < 16; ++i) {
    int idx = i * 256 + tid;
    int d = idx >> 6, kk = idx & 63;
    Vt[(size_t)(bh * 64 + d) * S_ + kt * 64 + kk] = t[kk * 66 + d];
  }
}

// ---------------- fused QK^T + bias + mask + exp -> unnormalized P + invl ----------------
__global__ __launch_bounds__(256, 4) void attn_scores_k(const u16* __restrict__ qkv,
                                                        const int* __restrict__ dist,
                                                        const float* __restrict__ dist_emb,
                                                        const int* __restrict__ vseq,
                                                        u16* __restrict__ P,
                                                        float* __restrict__ invl) {
  int blk = blockIdx.x;
  int bh = blk & 127;
  int qt = blk >> 7;
  int b = bh >> 4, h = bh & 15;
  int tid = threadIdx.x, wv = tid >> 6, ln = tid & 63;
  int lr = ln & 15, lk = ln >> 4;

  __shared__ float de[208];
  __shared__ unsigned char padf[512];
  __shared__ unsigned char d8[64 * 512];

  int ncol = (qt + 1) * 64;
  for (int i = tid; i < 208; i += 256)
    de[i] = (i < 200) ? dist_emb[i * H_ + h] : -1e30f;
  for (int i = tid; i < (ncol >> 2); i += 256) {
    int4 v = *reinterpret_cast<const int4*>(vseq + b * S_ + i * 4);
    uchar4 pz;
    pz.x = (v.x == 0); pz.y = (v.y == 0); pz.z = (v.z == 0); pz.w = (v.w == 0);
    *reinterpret_cast<uchar4*>(&padf[i * 4]) = pz;
  }
  __syncthreads();

  {
    int r = tid >> 2;
    const int* drow = dist + ((size_t)(b * S_ + qt * 64 + r) << 9);
    int nc4 = ncol >> 2;
    for (int c4 = (tid & 3); c4 < nc4; c4 += 4) {
      int4 dv = *reinterpret_cast<const int4*>(drow + c4 * 4);
      uchar4 o;
      o.x = padf[c4 * 4 + 0] ? (unsigned char)200 : (unsigned char)dv.x;
      o.y = padf[c4 * 4 + 1] ? (unsigned char)200 : (unsigned char)dv.y;
      o.z = padf[c4 * 4 + 2] ? (unsigned char)200 : (unsigned char)dv.z;
      o.w = padf[c4 * 4 + 3] ? (unsigned char)200 : (unsigned char)dv.w;
      *reinterpret_cast<uchar4*>(&d8[(r << 9) + c4 * 4]) = o;
    }
  }
  __syncthreads();

  int q0 = qt * 64 + wv * 16;
  int nv = 4 * qt + wv + 1;
  int nreq = 4 * qt + 2 * (wv >> 1) + 2;
  int qrow = q0 + lk * 4;
  int lrow = wv * 16 + lk * 4;

  bf16x8 aq0 = *reinterpret_cast<const bf16x8*>(
      qkv + (size_t)(b * S_ + q0 + lr) * 3072 + h * 64 + lk * 8);
  bf16x8 aq1 = *reinterpret_cast<const bf16x8*>(
      qkv + (size_t)(b * S_ + q0 + lr) * 3072 + h * 64 + 32 + lk * 8);

  float sm[4] = {0.f, 0.f, 0.f, 0.f};
  f32x4 z = {0.f, 0.f, 0.f, 0.f};
  int nch = (nv + 3) >> 2;
  #pragma unroll 1
  for (int c = 0; c < nch; ++c) {
    int base = c * 4;
    f32x4 acc[4] = {z, z, z, z};
    #pragma unroll
    for (int j = 0; j < 4; ++j) {
      int n = base + j;
      if (n < nv) {
        const u16* kb = qkv + (size_t)(b * S_ + n * 16 + lr) * 3072 + E_ + h * 64 + lk * 8;
        bf16x8 bk0 = *reinterpret_cast<const bf16x8*>(kb);
        bf16x8 bk1 = *reinterpret_cast<const bf16x8*>(kb + 32);
        acc[j] = __builtin_amdgcn_mfma_f32_16x16x32_bf16(aq0, bk0, acc[j], 0, 0, 0);
        acc[j] = __builtin_amdgcn_mfma_f32_16x16x32_bf16(aq1, bk1, acc[j], 0, 0, 0);
      }
    }
    #pragma unroll
    for (int j = 0; j < 4; ++j) {
      int n = base + j;
      if (n < nv) {
        int col = n * 16 + lr;
        #pragma unroll
        for (int r2 = 0; r2 < 4; ++r2) {
          float e = 0.f;
          if (col <= qrow + r2) {
            int d = d8[((lrow + r2) << 9) + col];
            e = __expf(acc[j][r2] * 0.125f + de[d]);
          }
          sm[r2] += e;
          P[(size_t)(bh * S_ + qrow + r2) * S_ + col] = f2bf(e);
        }
      }
    }
  }
  for (int n = nv; n < nreq; ++n) {
    int col = n * 16 + lr;
    #pragma unroll
    for (int r2 = 0; r2 < 4; ++r2)
      P[(size_t)(bh * S_ + qrow + r2) * S_ + col] = 0;
  }
  #pragma unroll
  for (int off = 1; off < 16; off <<= 1)
    #pragma unroll
    for (int r2 = 0; r2 < 4; ++r2) sm[r2] += __shfl_xor(sm[r2], off, 64);
  if (lr == 0) {
    #pragma unroll
    for (int r2 = 0; r2 < 4; ++r2)
      invl[bh * S_ + qrow + r2] = 1.f / sm[r2];
  }
}

// ---------------- ctx = (P @ V) * invl (via Vt) ----------------
__global__ __launch_bounds__(256) void attn_pv_k(const u16* __restrict__ P,
                                                 const u16* __restrict__ Vt,
                                                 const float* __restrict__ invl,
                                                 u16* __restrict__ ctx) {
  int blk = blockIdx.x;
  int mt = blk & 3, bh = blk >> 2;
  int b = bh >> 4, h = bh & 15;
  int tid = threadIdx.x, wv = tid >> 6, ln = tid & 63;
  int lr = ln & 15, lk = ln >> 4;
  int r0 = mt * 128 + wv * 32;
  f32x4 acc[2][4];
  f32x4 z = {0.f, 0.f, 0.f, 0.f};
  #pragma unroll
  for (int m = 0; m < 2; ++m)
    #pragma unroll
    for (int n = 0; n < 4; ++n) acc[m][n] = z;
  int nks = mt * 4 + wv + 1;
  for (int ks = 0; ks < nks; ++ks) {
    int k0 = ks * 32;
    bf16x8 ap[2];
    #pragma unroll
    for (int m = 0; m < 2; ++m)
      ap[m] = *reinterpret_cast<const bf16x8*>(
          P + (size_t)(bh * S_ + r0 + m * 16 + lr) * S_ + k0 + lk * 8);
    #pragma unroll
    for (int n = 0; n < 4; ++n) {
      bf16x8 bv = *reinterpret_cast<const bf16x8*>(
          Vt + (size_t)(bh * 64 + n * 16 + lr) * S_ + k0 + lk * 8);
      #pragma unroll
      for (int m = 0; m < 2; ++m)
        acc[m][n] = __builtin_amdgcn_mfma_f32_16x16x32_bf16(ap[m], bv, acc[m][n], 0, 0, 0);
    }
  }
  float il[2][4];
  #pragma unroll
  for (int m = 0; m < 2; ++m)
    #pragma unroll
    for (int r = 0; r < 4; ++r)
      il[m][r] = invl[bh * S_ + r0 + m * 16 + lk * 4 + r];
  #pragma unroll
  for (int m = 0; m < 2; ++m)
    #pragma unroll
    for (int n = 0; n < 4; ++n)
      #pragma unroll
      for (int r = 0; r < 4; ++r) {
        int row = r0 + m * 16 + lk * 4 + r;
        int col = n * 16 + lr;
        ctx[(size_t)(b * S_ + row) * E_ + h * 64 + col] = f2bf(acc[m][n][r] * il[m][r]);
      }
}

extern "C" void kernel_launch(void* const* d_in, const int* in_sizes, int n_in,
                              void* d_out, int out_size, void* d_ws, size_t ws_size,
                              hipStream_t stream) {
  const float* val_emb = (const float*)d_in[0];
  const float* ring_emb = (const float*)d_in[1];
  const float* dist_emb = (const float*)d_in[2];
  const float* Wqkv = (const float*)d_in[3];
  const float* bqkv = (const float*)d_in[4];
  const float* Wo = (const float*)d_in[5];
  const float* bo = (const float*)d_in[6];
  const float* ln1_s = (const float*)d_in[7];
  const float* ln1_b = (const float*)d_in[8];
  const float* W1 = (const float*)d_in[9];
  const float* b1 = (const float*)d_in[10];
  const float* W2 = (const float*)d_in[11];
  const float* b2 = (const float*)d_in[12];
  const float* ln2_s = (const float*)d_in[13];
  const float* ln2_b = (const float*)d_in[14];
  const float* lnf_s = (const float*)d_in[15];
  const float* lnf_b = (const float*)d_in[16];
  const float* gen_W = (const float*)d_in[17];
  const float* gen_b = (const float*)d_in[18];
  const int* vseq = (const int*)d_in[19];
  const int* rseq = (const int*)d_in[20];
  const int* dist = (const int*)d_in[21];

  char* ws = (char*)d_ws;
  size_t off = 0;
  auto alloc = [&](size_t nbytes) {
    char* p = ws + off;
    off += (nbytes + 255) & ~(size_t)255;
    return p;
  };
  u16* gw_bf = (u16*)alloc((size_t)GEN_N * E_ * 2);
  u16* wqkv_l = (u16*)alloc((size_t)3 * E_ * E_ * 2);
  u16* wo_l = (u16*)alloc((size_t)E_ * E_ * 2);
  u16* w1_l = (u16*)alloc((size_t)F_ * E_ * 2);
  u16* w2_l = (u16*)alloc((size_t)E_ * F_ * 2);
  float* h = (float*)alloc((size_t)T_ * E_ * 4);
  u16* x_bf = (u16*)alloc((size_t)T_ * E_ * 2);
  u16* qkv_bf = (u16*)alloc((size_t)T_ * 3 * E_ * 2);
  u16* ctx_bf = (u16*)alloc((size_t)T_ * E_ * 2);
  u16* vt_bf = (u16*)alloc((size_t)B_ * H_ * 64 * S_ * 2);
  float* invl = (float*)alloc((size_t)B_ * H_ * S_ * 4);
  u16* p_bf = (u16*)alloc((size_t)B_ * H_ * S_ * S_ * 2);
  u16* ff_bf = p_bf;  // aliased: P dead before FF is produced
  (void)ws_size; (void)in_sizes; (void)n_in; (void)out_size; (void)rseq;

  auto cvt = [&](const float* s, u16* d, int n) {
    cvt_bf16<<<dim3((n / 4 + 255) / 256), dim3(256), 0, stream>>>(s, d, n);
  };
  cvt(gen_W, gw_bf, GEN_N * E_);

  embed_k<<<dim3(T_), dim3(256), 0, stream>>>(val_emb, ring_emb, vseq, rseq, h, x_bf);

  for (int l = 0; l < L_; ++l) {
    cvt(Wqkv + (size_t)l * 3 * E_ * E_, wqkv_l, 3 * E_ * E_);
    cvt(Wo + (size_t)l * E_ * E_, wo_l, E_ * E_);
    cvt(W1 + (size_t)l * F_ * E_, w1_l, F_ * E_);
    cvt(W2 + (size_t)l * E_ * F_, w2_l, E_ * F_);

    gemm_bt<0><<<dim3(32 * 24), dim3(256), 0, stream>>>(
        x_bf, wqkv_l, bqkv + (size_t)l * 3 * E_, qkv_bf, T_, 3 * E_, E_, 24);
    vtrans_k<<<dim3(B_ * H_ * 8), dim3(256), 0, stream>>>(qkv_bf, vt_bf);
    attn_scores_k<<<dim3(B_ * H_ * 8), dim3(256), 0, stream>>>(qkv_bf, dist, dist_emb, vseq,
                                                               p_bf, invl);
    attn_pv_k<<<dim3(B_ * H_ * 4), dim3(256), 0, stream>>>(p_bf, vt_bf, invl, ctx_bf);
    gemm_bt<3><<<dim3(32 * 8), dim3(256), 0, stream>>>(
        ctx_bf, wo_l, bo + (size_t)l * E_, h, T_, E_, E_, 8);
    ln_k<<<dim3(T_), dim3(256), 0, stream>>>(h, ln1_s + (size_t)l * E_,
                                             ln1_b + (size_t)l * E_, h, x_bf);
    gemm_bt<1><<<dim3(32 * 32), dim3(256), 0, stream>>>(
        x_bf, w1_l, b1 + (size_t)l * F_, ff_bf, T_, F_, E_, 32);
    gemm_bt<3><<<dim3(32 * 8), dim3(256), 0, stream>>>(
        ff_bf, w2_l, b2 + (size_t)l * E_, h, T_, E_, F_, 8);
    ln_k<<<dim3(T_), dim3(256), 0, stream>>>(h, ln2_s + (size_t)l * E_,
                                             ln2_b + (size_t)l * E_, h, x_bf);
  }
  ln_k<<<dim3(T_), dim3(256), 0, stream>>>(h, lnf_s, lnf_b, nullptr, x_bf);
  gemm_bt<2><<<dim3(32 * 10), dim3(256), 0, stream>>>(
      x_bf, gw_bf, gen_b, (float*)d_out, T_, GEN_N, E_, 10);
}

// Round 7
// 1373.282 us; speedup vs baseline: 1.0438x; 1.0438x over previous
//
#include <hip/hip_runtime.h>
#include <hip/hip_bf16.h>

typedef __attribute__((ext_vector_type(8))) short bf16x8;
typedef __attribute__((ext_vector_type(4))) float f32x4;
typedef unsigned short u16;
typedef __attribute__((ext_vector_type(4))) unsigned short u16x4;

#define L_ 4
#define E_ 1024
#define H_ 16
#define F_ 4096
#define B_ 8
#define S_ 512
#define T_ 4096
#define GEN_N 1200

static __device__ __forceinline__ u16 f2bf(float f) {
  unsigned u = __float_as_uint(f);
  unsigned r = (u + 0x7fffu + ((u >> 16) & 1u)) >> 16;
  return (u16)r;
}

static __device__ __forceinline__ float fast_gelu(float v) {
  float y = 0.7978845608f * (v + 0.044715f * v * v * v);
  y = fminf(fmaxf(y, -9.f), 9.f);
  float e2 = __expf(2.f * y);
  float th = (e2 - 1.f) / (e2 + 1.f);
  return 0.5f * v * (1.f + th);
}

// ---------------- f32 -> bf16 convert ----------------
__global__ __launch_bounds__(256) void cvt_bf16(const float* __restrict__ src,
                                                u16* __restrict__ dst, int n) {
  int i = (blockIdx.x * 256 + threadIdx.x) * 4;
  if (i >= n) return;
  float4 v = *reinterpret_cast<const float4*>(src + i);
  u16x4 o = {f2bf(v.x), f2bf(v.y), f2bf(v.z), f2bf(v.w)};
  *reinterpret_cast<u16x4*>(dst + i) = o;
}

// ---------------- embedding ----------------
__global__ __launch_bounds__(256) void embed_k(const float* __restrict__ val_emb,
                                               const float* __restrict__ ring_emb,
                                               const int* __restrict__ vseq,
                                               const int* __restrict__ rseq,
                                               float* __restrict__ h, u16* __restrict__ xbf) {
  int tok = blockIdx.x;
  int e = threadIdx.x * 4;
  int v = vseq[tok], r = rseq[tok];
  float4 a = *reinterpret_cast<const float4*>(val_emb + v * E_ + e);
  float4 b = *reinterpret_cast<const float4*>(ring_emb + r * E_ + e);
  float4 o;
  o.x = (a.x + b.x) * 32.f; o.y = (a.y + b.y) * 32.f;
  o.z = (a.z + b.z) * 32.f; o.w = (a.w + b.w) * 32.f;
  *reinterpret_cast<float4*>(h + (size_t)tok * E_ + e) = o;
  u16x4 ob = {f2bf(o.x), f2bf(o.y), f2bf(o.z), f2bf(o.w)};
  *reinterpret_cast<u16x4*>(xbf + (size_t)tok * E_ + e) = ob;
}

// ---------------- LayerNorm ----------------
__global__ __launch_bounds__(256) void ln_k(const float* hin,
                                            const float* g, const float* bta,
                                            float* hout, u16* xout) {
  int tok = blockIdx.x;
  int e = threadIdx.x * 4;
  float4 v = *reinterpret_cast<const float4*>(hin + (size_t)tok * E_ + e);
  float s = v.x + v.y + v.z + v.w;
  float q = v.x * v.x + v.y * v.y + v.z * v.z + v.w * v.w;
  #pragma unroll
  for (int off = 1; off < 64; off <<= 1) {
    s += __shfl_xor(s, off, 64);
    q += __shfl_xor(q, off, 64);
  }
  __shared__ float ls[4], lq[4];
  int wv = threadIdx.x >> 6, ln = threadIdx.x & 63;
  if (ln == 0) { ls[wv] = s; lq[wv] = q; }
  __syncthreads();
  s = ls[0] + ls[1] + ls[2] + ls[3];
  q = lq[0] + lq[1] + lq[2] + lq[3];
  float mean = s * (1.f / E_);
  float var = q * (1.f / E_) - mean * mean;
  float inv = rsqrtf(var + 1e-5f);
  float4 gg = *reinterpret_cast<const float4*>(g + e);
  float4 bb = *reinterpret_cast<const float4*>(bta + e);
  float4 o;
  o.x = (v.x - mean) * inv * gg.x + bb.x;
  o.y = (v.y - mean) * inv * gg.y + bb.y;
  o.z = (v.z - mean) * inv * gg.z + bb.z;
  o.w = (v.w - mean) * inv * gg.w + bb.w;
  if (hout) *reinterpret_cast<float4*>(hout + (size_t)tok * E_ + e) = o;
  u16x4 ob = {f2bf(o.x), f2bf(o.y), f2bf(o.z), f2bf(o.w)};
  *reinterpret_cast<u16x4*>(xout + (size_t)tok * E_ + e) = ob;
}

// ---------------- GEMM: C[M,N] = A[M,K] @ W[N,K]^T + bias ----------------
// Triple-buffered LDS, depth-2 prefetch with counted vmcnt across raw barriers:
// steady state keeps tiles t+1,t+2 (8 loads) in flight across both barriers.
// EPI: 0 = bf16 out, 1 = gelu -> bf16 out, 2 = f32 out, 3 = f32 accumulate
template <int EPI>
__global__ __launch_bounds__(256) void gemm_bt(const u16* __restrict__ A,
                                               const u16* __restrict__ W,
                                               const float* __restrict__ bias,
                                               void* __restrict__ Cp,
                                               int M, int N, int K, int tilesN) {
  __shared__ __align__(16) u16 As[3][128 * 32];
  __shared__ __align__(16) u16 Bs[3][128 * 32];
  int tid = threadIdx.x;
  int wv = tid >> 6, ln = tid & 63;
  int wm = wv >> 1, wn = wv & 1;
  int nwg = gridDim.x;
  int bid = blockIdx.x;
  int swz = ((nwg & 7) == 0) ? ((bid & 7) * (nwg >> 3) + (bid >> 3)) : bid;
  int tm = swz / tilesN, tn = swz % tilesN;
  int row0 = tm * 128, col0 = tn * 128;
  int lr = ln & 15, lk = ln >> 4;

  f32x4 acc[4][4];
  f32x4 z = {0.f, 0.f, 0.f, 0.f};
  #pragma unroll
  for (int m = 0; m < 4; ++m)
    #pragma unroll
    for (int n = 0; n < 4; ++n) acc[m][n] = z;

  // staging coords: thread -> (row srow, k-chunk), source chunk XOR-swizzled
  int srow = tid >> 2;
  int scol = ((tid & 3) ^ (srow & 3)) * 8;
  const u16* gA0 = A + (size_t)(row0 + srow) * K + scol;
  const u16* gA1 = A + (size_t)(row0 + 64 + srow) * K + scol;
  int wr0 = col0 + srow;      if (wr0 >= N) wr0 = N - 1;
  int wr1 = col0 + 64 + srow; if (wr1 >= N) wr1 = N - 1;
  const u16* gB0 = W + (size_t)wr0 * K + scol;
  const u16* gB1 = W + (size_t)wr1 * K + scol;
  size_t ldsOff0 = (size_t)(wv << 6) * 16;
  size_t ldsOff1 = (size_t)(256 + (wv << 6)) * 16;

  auto stage = [&](int buf, int k0) {
    __builtin_amdgcn_global_load_lds(
        (const __attribute__((address_space(1))) void*)(gA0 + k0),
        (__attribute__((address_space(3))) void*)((char*)&As[buf][0] + ldsOff0), 16, 0, 0);
    __builtin_amdgcn_global_load_lds(
        (const __attribute__((address_space(1))) void*)(gB0 + k0),
        (__attribute__((address_space(3))) void*)((char*)&Bs[buf][0] + ldsOff0), 16, 0, 0);
    __builtin_amdgcn_global_load_lds(
        (const __attribute__((address_space(1))) void*)(gA1 + k0),
        (__attribute__((address_space(3))) void*)((char*)&As[buf][0] + ldsOff1), 16, 0, 0);
    __builtin_amdgcn_global_load_lds(
        (const __attribute__((address_space(1))) void*)(gB1 + k0),
        (__attribute__((address_space(3))) void*)((char*)&Bs[buf][0] + ldsOff1), 16, 0, 0);
  };

  int ck = (lk ^ (lr & 3)) * 8;
  auto compute = [&](int buf) {
    bf16x8 af[4], bfr[4];
    #pragma unroll
    for (int m = 0; m < 4; ++m)
      af[m] = *reinterpret_cast<const bf16x8*>(&As[buf][(wm * 64 + m * 16 + lr) * 32 + ck]);
    #pragma unroll
    for (int n = 0; n < 4; ++n)
      bfr[n] = *reinterpret_cast<const bf16x8*>(&Bs[buf][(wn * 64 + n * 16 + lr) * 32 + ck]);
    #pragma unroll
    for (int m = 0; m < 4; ++m)
      #pragma unroll
      for (int n = 0; n < 4; ++n)
        acc[m][n] = __builtin_amdgcn_mfma_f32_16x16x32_bf16(af[m], bfr[n], acc[m][n], 0, 0, 0);
  };

  int nsteps = K >> 5;               // >= 32 for all our shapes
  stage(0, 0);
  stage(1, 32);
  int bt = 0;                        // buffer holding tile t
  for (int t = 0; t < nsteps; ++t) {
    int rem = nsteps - 1 - t;        // tiles after t
    if (rem >= 2) {
      int b2 = (bt == 0) ? 2 : bt - 1;   // (bt+2)%3
      stage(b2, (t + 2) << 5);
      asm volatile("s_waitcnt vmcnt(8)" ::: "memory");  // tile t arrived; t+1,t+2 in flight
    } else if (rem == 1) {
      asm volatile("s_waitcnt vmcnt(4)" ::: "memory");  // tile t arrived; t+1 in flight
    } else {
      asm volatile("s_waitcnt vmcnt(0)" ::: "memory");
    }
    __builtin_amdgcn_s_barrier();    // all waves' tile-t loads complete
    asm volatile("" ::: "memory");
    compute(bt);
    asm volatile("" ::: "memory");
    __builtin_amdgcn_s_barrier();    // all readers of buf bt done -> reusable
    bt = (bt == 2) ? 0 : bt + 1;
  }

  #pragma unroll
  for (int n = 0; n < 4; ++n) {
    int col = col0 + wn * 64 + n * 16 + lr;
    if (col >= N) continue;
    float bv = bias[col];
    #pragma unroll
    for (int m = 0; m < 4; ++m) {
      int rbase = row0 + wm * 64 + m * 16 + lk * 4;
      #pragma unroll
      for (int r2 = 0; r2 < 4; ++r2) {
        float v = acc[m][n][r2] + bv;
        if (EPI == 1) v = fast_gelu(v);
        int row = rbase + r2;
        if (EPI == 2)
          ((float*)Cp)[(size_t)row * N + col] = v;
        else if (EPI == 3)
          ((float*)Cp)[(size_t)row * N + col] += v;
        else
          ((u16*)Cp)[(size_t)row * N + col] = f2bf(v);
      }
    }
  }
}

// ---------------- V transpose: Vt[bh][d][k] = V[bh][k][d] ----------------
__global__ __launch_bounds__(256) void vtrans_k(const u16* __restrict__ qkv,
                                                u16* __restrict__ Vt) {
  int blk = blockIdx.x;
  int kt = blk & 7, bh = blk >> 3;
  int b = bh >> 4, h = bh & 15;
  __shared__ u16 t[64 * 66];
  int tid = threadIdx.x;
  #pragma unroll
  for (int i = 0; i < 16; ++i) {
    int idx = i * 256 + tid;
    int kk = idx >> 6, d = idx & 63;
    t[kk * 66 + d] = qkv[(size_t)(b * S_ + kt * 64 + kk) * 3072 + 2 * E_ + h * 64 + d];
  }
  __syncthreads();
  #pragma unroll
  for (int i = 0; i < 16; ++i) {
    int idx = i * 256 + tid;
    int d = idx >> 6, kk = idx & 63;
    Vt[(size_t)(bh * 64 + d) * S_ + kt * 64 + kk] = t[kk * 66 + d];
  }
}

// ---------------- fused QK^T + bias + mask + exp -> unnormalized P + invl ----------------
__global__ __launch_bounds__(256, 4) void attn_scores_k(const u16* __restrict__ qkv,
                                                        const int* __restrict__ dist,
                                                        const float* __restrict__ dist_emb,
                                                        const int* __restrict__ vseq,
                                                        u16* __restrict__ P,
                                                        float* __restrict__ invl) {
  int blk = blockIdx.x;
  int bh = blk & 127;
  int qt = blk >> 7;
  int b = bh >> 4, h = bh & 15;
  int tid = threadIdx.x, wv = tid >> 6, ln = tid & 63;
  int lr = ln & 15, lk = ln >> 4;

  __shared__ float de[208];
  __shared__ unsigned char padf[512];
  __shared__ unsigned char d8[64 * 512];

  int ncol = (qt + 1) * 64;
  for (int i = tid; i < 208; i += 256)
    de[i] = (i < 200) ? dist_emb[i * H_ + h] : -1e30f;
  for (int i = tid; i < (ncol >> 2); i += 256) {
    int4 v = *reinterpret_cast<const int4*>(vseq + b * S_ + i * 4);
    uchar4 pz;
    pz.x = (v.x == 0); pz.y = (v.y == 0); pz.z = (v.z == 0); pz.w = (v.w == 0);
    *reinterpret_cast<uchar4*>(&padf[i * 4]) = pz;
  }
  __syncthreads();

  {
    int r = tid >> 2;
    const int* drow = dist + ((size_t)(b * S_ + qt * 64 + r) << 9);
    int nc4 = ncol >> 2;
    for (int c4 = (tid & 3); c4 < nc4; c4 += 4) {
      int4 dv = *reinterpret_cast<const int4*>(drow + c4 * 4);
      uchar4 o;
      o.x = padf[c4 * 4 + 0] ? (unsigned char)200 : (unsigned char)dv.x;
      o.y = padf[c4 * 4 + 1] ? (unsigned char)200 : (unsigned char)dv.y;
      o.z = padf[c4 * 4 + 2] ? (unsigned char)200 : (unsigned char)dv.z;
      o.w = padf[c4 * 4 + 3] ? (unsigned char)200 : (unsigned char)dv.w;
      *reinterpret_cast<uchar4*>(&d8[(r << 9) + c4 * 4]) = o;
    }
  }
  __syncthreads();

  int q0 = qt * 64 + wv * 16;
  int nv = 4 * qt + wv + 1;
  int nreq = 4 * qt + 2 * (wv >> 1) + 2;
  int qrow = q0 + lk * 4;
  int lrow = wv * 16 + lk * 4;

  bf16x8 aq0 = *reinterpret_cast<const bf16x8*>(
      qkv + (size_t)(b * S_ + q0 + lr) * 3072 + h * 64 + lk * 8);
  bf16x8 aq1 = *reinterpret_cast<const bf16x8*>(
      qkv + (size_t)(b * S_ + q0 + lr) * 3072 + h * 64 + 32 + lk * 8);

  float sm[4] = {0.f, 0.f, 0.f, 0.f};
  f32x4 z = {0.f, 0.f, 0.f, 0.f};
  int nch = (nv + 3) >> 2;
  #pragma unroll 1
  for (int c = 0; c < nch; ++c) {
    int base = c * 4;
    f32x4 acc[4] = {z, z, z, z};
    #pragma unroll
    for (int j = 0; j < 4; ++j) {
      int n = base + j;
      if (n < nv) {
        const u16* kb = qkv + (size_t)(b * S_ + n * 16 + lr) * 3072 + E_ + h * 64 + lk * 8;
        bf16x8 bk0 = *reinterpret_cast<const bf16x8*>(kb);
        bf16x8 bk1 = *reinterpret_cast<const bf16x8*>(kb + 32);
        acc[j] = __builtin_amdgcn_mfma_f32_16x16x32_bf16(aq0, bk0, acc[j], 0, 0, 0);
        acc[j] = __builtin_amdgcn_mfma_f32_16x16x32_bf16(aq1, bk1, acc[j], 0, 0, 0);
      }
    }
    #pragma unroll
    for (int j = 0; j < 4; ++j) {
      int n = base + j;
      if (n < nv) {
        int col = n * 16 + lr;
        #pragma unroll
        for (int r2 = 0; r2 < 4; ++r2) {
          float e = 0.f;
          if (col <= qrow + r2) {
            int d = d8[((lrow + r2) << 9) + col];
            e = __expf(acc[j][r2] * 0.125f + de[d]);
          }
          sm[r2] += e;
          P[(size_t)(bh * S_ + qrow + r2) * S_ + col] = f2bf(e);
        }
      }
    }
  }
  for (int n = nv; n < nreq; ++n) {
    int col = n * 16 + lr;
    #pragma unroll
    for (int r2 = 0; r2 < 4; ++r2)
      P[(size_t)(bh * S_ + qrow + r2) * S_ + col] = 0;
  }
  #pragma unroll
  for (int off = 1; off < 16; off <<= 1)
    #pragma unroll
    for (int r2 = 0; r2 < 4; ++r2) sm[r2] += __shfl_xor(sm[r2], off, 64);
  if (lr == 0) {
    #pragma unroll
    for (int r2 = 0; r2 < 4; ++r2)
      invl[bh * S_ + qrow + r2] = 1.f / sm[r2];
  }
}

// ---------------- ctx = (P @ V) * invl (via Vt) ----------------
__global__ __launch_bounds__(256) void attn_pv_k(const u16* __restrict__ P,
                                                 const u16* __restrict__ Vt,
                                                 const float* __restrict__ invl,
                                                 u16* __restrict__ ctx) {
  int blk = blockIdx.x;
  int mt = blk & 3, bh = blk >> 2;
  int b = bh >> 4, h = bh & 15;
  int tid = threadIdx.x, wv = tid >> 6, ln = tid & 63;
  int lr = ln & 15, lk = ln >> 4;
  int r0 = mt * 128 + wv * 32;
  f32x4 acc[2][4];
  f32x4 z = {0.f, 0.f, 0.f, 0.f};
  #pragma unroll
  for (int m = 0; m < 2; ++m)
    #pragma unroll
    for (int n = 0; n < 4; ++n) acc[m][n] = z;
  int nks = mt * 4 + wv + 1;
  for (int ks = 0; ks < nks; ++ks) {
    int k0 = ks * 32;
    bf16x8 ap[2];
    #pragma unroll
    for (int m = 0; m < 2; ++m)
      ap[m] = *reinterpret_cast<const bf16x8*>(
          P + (size_t)(bh * S_ + r0 + m * 16 + lr) * S_ + k0 + lk * 8);
    #pragma unroll
    for (int n = 0; n < 4; ++n) {
      bf16x8 bv = *reinterpret_cast<const bf16x8*>(
          Vt + (size_t)(bh * 64 + n * 16 + lr) * S_ + k0 + lk * 8);
      #pragma unroll
      for (int m = 0; m < 2; ++m)
        acc[m][n] = __builtin_amdgcn_mfma_f32_16x16x32_bf16(ap[m], bv, acc[m][n], 0, 0, 0);
    }
  }
  float il[2][4];
  #pragma unroll
  for (int m = 0; m < 2; ++m)
    #pragma unroll
    for (int r = 0; r < 4; ++r)
      il[m][r] = invl[bh * S_ + r0 + m * 16 + lk * 4 + r];
  #pragma unroll
  for (int m = 0; m < 2; ++m)
    #pragma unroll
    for (int n = 0; n < 4; ++n)
      #pragma unroll
      for (int r = 0; r < 4; ++r) {
        int row = r0 + m * 16 + lk * 4 + r;
        int col = n * 16 + lr;
        ctx[(size_t)(b * S_ + row) * E_ + h * 64 + col] = f2bf(acc[m][n][r] * il[m][r]);
      }
}

extern "C" void kernel_launch(void* const* d_in, const int* in_sizes, int n_in,
                              void* d_out, int out_size, void* d_ws, size_t ws_size,
                              hipStream_t stream) {
  const float* val_emb = (const float*)d_in[0];
  const float* ring_emb = (const float*)d_in[1];
  const float* dist_emb = (const float*)d_in[2];
  const float* Wqkv = (const float*)d_in[3];
  const float* bqkv = (const float*)d_in[4];
  const float* Wo = (const float*)d_in[5];
  const float* bo = (const float*)d_in[6];
  const float* ln1_s = (const float*)d_in[7];
  const float* ln1_b = (const float*)d_in[8];
  const float* W1 = (const float*)d_in[9];
  const float* b1 = (const float*)d_in[10];
  const float* W2 = (const float*)d_in[11];
  const float* b2 = (const float*)d_in[12];
  const float* ln2_s = (const float*)d_in[13];
  const float* ln2_b = (const float*)d_in[14];
  const float* lnf_s = (const float*)d_in[15];
  const float* lnf_b = (const float*)d_in[16];
  const float* gen_W = (const float*)d_in[17];
  const float* gen_b = (const float*)d_in[18];
  const int* vseq = (const int*)d_in[19];
  const int* rseq = (const int*)d_in[20];
  const int* dist = (const int*)d_in[21];

  char* ws = (char*)d_ws;
  size_t off = 0;
  auto alloc = [&](size_t nbytes) {
    char* p = ws + off;
    off += (nbytes + 255) & ~(size_t)255;
    return p;
  };
  u16* gw_bf = (u16*)alloc((size_t)GEN_N * E_ * 2);
  u16* wqkv_l = (u16*)alloc((size_t)3 * E_ * E_ * 2);
  u16* wo_l = (u16*)alloc((size_t)E_ * E_ * 2);
  u16* w1_l = (u16*)alloc((size_t)F_ * E_ * 2);
  u16* w2_l = (u16*)alloc((size_t)E_ * F_ * 2);
  float* h = (float*)alloc((size_t)T_ * E_ * 4);
  u16* x_bf = (u16*)alloc((size_t)T_ * E_ * 2);
  u16* qkv_bf = (u16*)alloc((size_t)T_ * 3 * E_ * 2);
  u16* ctx_bf = (u16*)alloc((size_t)T_ * E_ * 2);
  u16* vt_bf = (u16*)alloc((size_t)B_ * H_ * 64 * S_ * 2);
  float* invl = (float*)alloc((size_t)B_ * H_ * S_ * 4);
  u16* p_bf = (u16*)alloc((size_t)B_ * H_ * S_ * S_ * 2);
  u16* ff_bf = p_bf;  // aliased: P dead before FF is produced
  (void)ws_size; (void)in_sizes; (void)n_in; (void)out_size; (void)rseq;

  auto cvt = [&](const float* s, u16* d, int n) {
    cvt_bf16<<<dim3((n / 4 + 255) / 256), dim3(256), 0, stream>>>(s, d, n);
  };
  cvt(gen_W, gw_bf, GEN_N * E_);

  embed_k<<<dim3(T_), dim3(256), 0, stream>>>(val_emb, ring_emb, vseq, rseq, h, x_bf);

  for (int l = 0; l < L_; ++l) {
    cvt(Wqkv + (size_t)l * 3 * E_ * E_, wqkv_l, 3 * E_ * E_);
    cvt(Wo + (size_t)l * E_ * E_, wo_l, E_ * E_);
    cvt(W1 + (size_t)l * F_ * E_, w1_l, F_ * E_);
    cvt(W2 + (size_t)l * E_ * F_, w2_l, E_ * F_);

    gemm_bt<0><<<dim3(32 * 24), dim3(256), 0, stream>>>(
        x_bf, wqkv_l, bqkv + (size_t)l * 3 * E_, qkv_bf, T_, 3 * E_, E_, 24);
    vtrans_k<<<dim3(B_ * H_ * 8), dim3(256), 0, stream>>>(qkv_bf, vt_bf);
    attn_scores_k<<<dim3(B_ * H_ * 8), dim3(256), 0, stream>>>(qkv_bf, dist, dist_emb, vseq,
                                                               p_bf, invl);
    attn_pv_k<<<dim3(B_ * H_ * 4), dim3(256), 0, stream>>>(p_bf, vt_bf, invl, ctx_bf);
    gemm_bt<3><<<dim3(32 * 8), dim3(256), 0, stream>>>(
        ctx_bf, wo_l, bo + (size_t)l * E_, h, T_, E_, E_, 8);
    ln_k<<<dim3(T_), dim3(256), 0, stream>>>(h, ln1_s + (size_t)l * E_,
                                             ln1_b + (size_t)l * E_, h, x_bf);
    gemm_bt<1><<<dim3(32 * 32), dim3(256), 0, stream>>>(
        x_bf, w1_l, b1 + (size_t)l * F_, ff_bf, T_, F_, E_, 32);
    gemm_bt<3><<<dim3(32 * 8), dim3(256), 0, stream>>>(
        ff_bf, w2_l, b2 + (size_t)l * E_, h, T_, E_, F_, 8);
    ln_k<<<dim3(T_), dim3(256), 0, stream>>>(h, ln2_s + (size_t)l * E_,
                                             ln2_b + (size_t)l * E_, h, x_bf);
  }
  ln_k<<<dim3(T_), dim3(256), 0, stream>>>(h, lnf_s, lnf_b, nullptr, x_bf);
  gemm_bt<2><<<dim3(32 * 10), dim3(256), 0, stream>>>(
      x_bf, gw_bf, gen_b, (float*)d_out, T_, GEN_N, E_, 10);
}

// Round 8
// 1334.011 us; speedup vs baseline: 1.0745x; 1.0294x over previous
//
#include <hip/hip_runtime.h>
#include <hip/hip_bf16.h>

typedef __attribute__((ext_vector_type(8))) short bf16x8;
typedef __attribute__((ext_vector_type(4))) float f32x4;
typedef unsigned short u16;
typedef __attribute__((ext_vector_type(4))) unsigned short u16x4;

#define L_ 4
#define E_ 1024
#define H_ 16
#define F_ 4096
#define B_ 8
#define S_ 512
#define T_ 4096
#define GEN_N 1200

#define AS1 __attribute__((address_space(1)))
#define AS3 __attribute__((address_space(3)))

static __device__ __forceinline__ u16 f2bf(float f) {
  unsigned u = __float_as_uint(f);
  unsigned r = (u + 0x7fffu + ((u >> 16) & 1u)) >> 16;
  return (u16)r;
}

static __device__ __forceinline__ float fast_gelu(float v) {
  float y = 0.7978845608f * (v + 0.044715f * v * v * v);
  y = fminf(fmaxf(y, -9.f), 9.f);
  float e2 = __expf(2.f * y);
  float th = (e2 - 1.f) / (e2 + 1.f);
  return 0.5f * v * (1.f + th);
}

// ---------------- f32 -> bf16 convert ----------------
__global__ __launch_bounds__(256) void cvt_bf16(const float* __restrict__ src,
                                                u16* __restrict__ dst, int n) {
  int i = (blockIdx.x * 256 + threadIdx.x) * 4;
  if (i >= n) return;
  float4 v = *reinterpret_cast<const float4*>(src + i);
  u16x4 o = {f2bf(v.x), f2bf(v.y), f2bf(v.z), f2bf(v.w)};
  *reinterpret_cast<u16x4*>(dst + i) = o;
}

// ---------------- embedding ----------------
__global__ __launch_bounds__(256) void embed_k(const float* __restrict__ val_emb,
                                               const float* __restrict__ ring_emb,
                                               const int* __restrict__ vseq,
                                               const int* __restrict__ rseq,
                                               float* __restrict__ h, u16* __restrict__ xbf) {
  int tok = blockIdx.x;
  int e = threadIdx.x * 4;
  int v = vseq[tok], r = rseq[tok];
  float4 a = *reinterpret_cast<const float4*>(val_emb + v * E_ + e);
  float4 b = *reinterpret_cast<const float4*>(ring_emb + r * E_ + e);
  float4 o;
  o.x = (a.x + b.x) * 32.f; o.y = (a.y + b.y) * 32.f;
  o.z = (a.z + b.z) * 32.f; o.w = (a.w + b.w) * 32.f;
  *reinterpret_cast<float4*>(h + (size_t)tok * E_ + e) = o;
  u16x4 ob = {f2bf(o.x), f2bf(o.y), f2bf(o.z), f2bf(o.w)};
  *reinterpret_cast<u16x4*>(xbf + (size_t)tok * E_ + e) = ob;
}

// ---------------- LayerNorm ----------------
__global__ __launch_bounds__(256) void ln_k(const float* hin,
                                            const float* g, const float* bta,
                                            float* hout, u16* xout) {
  int tok = blockIdx.x;
  int e = threadIdx.x * 4;
  float4 v = *reinterpret_cast<const float4*>(hin + (size_t)tok * E_ + e);
  float s = v.x + v.y + v.z + v.w;
  float q = v.x * v.x + v.y * v.y + v.z * v.z + v.w * v.w;
  #pragma unroll
  for (int off = 1; off < 64; off <<= 1) {
    s += __shfl_xor(s, off, 64);
    q += __shfl_xor(q, off, 64);
  }
  __shared__ float ls[4], lq[4];
  int wv = threadIdx.x >> 6, ln = threadIdx.x & 63;
  if (ln == 0) { ls[wv] = s; lq[wv] = q; }
  __syncthreads();
  s = ls[0] + ls[1] + ls[2] + ls[3];
  q = lq[0] + lq[1] + lq[2] + lq[3];
  float mean = s * (1.f / E_);
  float var = q * (1.f / E_) - mean * mean;
  float inv = rsqrtf(var + 1e-5f);
  float4 gg = *reinterpret_cast<const float4*>(g + e);
  float4 bb = *reinterpret_cast<const float4*>(bta + e);
  float4 o;
  o.x = (v.x - mean) * inv * gg.x + bb.x;
  o.y = (v.y - mean) * inv * gg.y + bb.y;
  o.z = (v.z - mean) * inv * gg.z + bb.z;
  o.w = (v.w - mean) * inv * gg.w + bb.w;
  if (hout) *reinterpret_cast<float4*>(hout + (size_t)tok * E_ + e) = o;
  u16x4 ob = {f2bf(o.x), f2bf(o.y), f2bf(o.z), f2bf(o.w)};
  *reinterpret_cast<u16x4*>(xout + (size_t)tok * E_ + e) = ob;
}

// ---------------- 256x256 deep-pipelined GEMM: C = A[M,K] @ W[N,K]^T + bias ----
// 512 threads = 8 waves (2Mx4N), per-wave 128x64 output, BK=64, dbuf 128KB LDS.
// T2 swizzle: LDS chunk ^= row&7 (pre-swizzled global src + swizzled ds_read).
// Counted vmcnt(8) across raw barriers (prefetch stays in flight).
// EPI: 0 = bf16 out, 1 = gelu -> bf16 out
template <int EPI>
__global__ __launch_bounds__(512, 2) void gemm256(const u16* __restrict__ A,
                                                  const u16* __restrict__ W,
                                                  const float* __restrict__ bias,
                                                  void* __restrict__ Cp,
                                                  int M, int N, int K, int tilesN) {
  __shared__ __align__(16) u16 As[2][256 * 64];
  __shared__ __align__(16) u16 Bs[2][256 * 64];
  int tid = threadIdx.x;
  int wid = tid >> 6, ln = tid & 63;
  int wm = wid >> 2, wn = wid & 3;
  int lr = ln & 15, lk = ln >> 4;
  int nwg = gridDim.x;
  int bid = blockIdx.x;
  int swz = ((nwg & 7) == 0) ? ((bid & 7) * (nwg >> 3) + (bid >> 3)) : bid;
  int tm = swz / tilesN, tn = swz % tilesN;
  int row0 = tm * 256, col0 = tn * 256;

  // staging: thread -> row (tid>>3), chunk (tid&7) pre-swizzled by row&7
  int srow = tid >> 3;                                  // 0..63 (+64*i per pass)
  int schunk = ((tid & 7) ^ (srow & 7)) * 8;            // u16 units
  const u16* gA = A + (size_t)(row0 + srow) * K + schunk;
  const u16* gB = W + (size_t)(col0 + srow) * K + schunk;
  size_t ldsBase = (size_t)((wid << 3) * 64) * 2;       // bytes; +i*64 rows per pass

  auto stage = [&](int buf, int kt) {
    size_t ko = (size_t)kt * 64;
    #pragma unroll
    for (int i = 0; i < 4; ++i) {
      __builtin_amdgcn_global_load_lds(
          (const AS1 void*)(gA + (size_t)i * 64 * K + ko),
          (AS3 void*)((char*)&As[buf][0] + ldsBase + (size_t)i * 64 * 128), 16, 0, 0);
      __builtin_amdgcn_global_load_lds(
          (const AS1 void*)(gB + (size_t)i * 64 * K + ko),
          (AS3 void*)((char*)&Bs[buf][0] + ldsBase + (size_t)i * 64 * 128), 16, 0, 0);
    }
  };

  f32x4 acc[8][4];
  f32x4 z = {0.f, 0.f, 0.f, 0.f};
  #pragma unroll
  for (int m = 0; m < 8; ++m)
    #pragma unroll
    for (int n = 0; n < 4; ++n) acc[m][n] = z;

  auto compute = [&](int buf) {
    #pragma unroll
    for (int s = 0; s < 2; ++s) {
      int ch = ((s * 4 + lk) ^ (lr & 7)) * 8;  // swizzled k-chunk (u16)
      bf16x8 bf4[4];
      #pragma unroll
      for (int n = 0; n < 4; ++n) {
        int br = wn * 64 + n * 16 + lr;
        bf4[n] = *reinterpret_cast<const bf16x8*>(&Bs[buf][br * 64 + ch]);
      }
      #pragma unroll
      for (int m = 0; m < 8; ++m) {
        int ar = wm * 128 + m * 16 + lr;
        bf16x8 af = *reinterpret_cast<const bf16x8*>(&As[buf][ar * 64 + ch]);
        #pragma unroll
        for (int n = 0; n < 4; ++n)
          acc[m][n] = __builtin_amdgcn_mfma_f32_16x16x32_bf16(af, bf4[n], acc[m][n], 0, 0, 0);
      }
    }
  };

  int nt = K >> 6;
  stage(0, 0);
  int cur = 0;
  for (int t = 0; t < nt; ++t) {
    if (t + 1 < nt) {
      stage(cur ^ 1, t + 1);
      asm volatile("s_waitcnt vmcnt(8)" ::: "memory");  // tile t's 8 loads done
    } else {
      asm volatile("s_waitcnt vmcnt(0)" ::: "memory");
    }
    __builtin_amdgcn_s_barrier();
    asm volatile("" ::: "memory");
    compute(cur);
    asm volatile("" ::: "memory");
    __builtin_amdgcn_s_barrier();
    cur ^= 1;
  }

  #pragma unroll
  for (int n = 0; n < 4; ++n) {
    int col = col0 + wn * 64 + n * 16 + lr;
    float bv = bias[col];
    #pragma unroll
    for (int m = 0; m < 8; ++m) {
      int rbase = row0 + wm * 128 + m * 16 + lk * 4;
      #pragma unroll
      for (int r2 = 0; r2 < 4; ++r2) {
        float v = acc[m][n][r2] + bv;
        if (EPI == 1) v = fast_gelu(v);
        ((u16*)Cp)[(size_t)(rbase + r2) * N + col] = f2bf(v);
      }
    }
  }
}

// ---------------- 128x128 GEMM (kept for Wo / W2 / gen) ----------------
// EPI: 0 = bf16 out, 1 = gelu -> bf16 out, 2 = f32 out, 3 = f32 accumulate
template <int EPI>
__global__ __launch_bounds__(256) void gemm_bt(const u16* __restrict__ A,
                                               const u16* __restrict__ W,
                                               const float* __restrict__ bias,
                                               void* __restrict__ Cp,
                                               int M, int N, int K, int tilesN) {
  __shared__ __align__(16) u16 As[3][128 * 32];
  __shared__ __align__(16) u16 Bs[3][128 * 32];
  int tid = threadIdx.x;
  int wv = tid >> 6, ln = tid & 63;
  int wm = wv >> 1, wn = wv & 1;
  int nwg = gridDim.x;
  int bid = blockIdx.x;
  int swz = ((nwg & 7) == 0) ? ((bid & 7) * (nwg >> 3) + (bid >> 3)) : bid;
  int tm = swz / tilesN, tn = swz % tilesN;
  int row0 = tm * 128, col0 = tn * 128;
  int lr = ln & 15, lk = ln >> 4;

  f32x4 acc[4][4];
  f32x4 z = {0.f, 0.f, 0.f, 0.f};
  #pragma unroll
  for (int m = 0; m < 4; ++m)
    #pragma unroll
    for (int n = 0; n < 4; ++n) acc[m][n] = z;

  int srow = tid >> 2;
  int scol = ((tid & 3) ^ (srow & 3)) * 8;
  const u16* gA0 = A + (size_t)(row0 + srow) * K + scol;
  const u16* gA1 = A + (size_t)(row0 + 64 + srow) * K + scol;
  int wr0 = col0 + srow;      if (wr0 >= N) wr0 = N - 1;
  int wr1 = col0 + 64 + srow; if (wr1 >= N) wr1 = N - 1;
  const u16* gB0 = W + (size_t)wr0 * K + scol;
  const u16* gB1 = W + (size_t)wr1 * K + scol;
  size_t ldsOff0 = (size_t)(wv << 6) * 16;
  size_t ldsOff1 = (size_t)(256 + (wv << 6)) * 16;

  auto stage = [&](int buf, int k0) {
    __builtin_amdgcn_global_load_lds((const AS1 void*)(gA0 + k0),
        (AS3 void*)((char*)&As[buf][0] + ldsOff0), 16, 0, 0);
    __builtin_amdgcn_global_load_lds((const AS1 void*)(gB0 + k0),
        (AS3 void*)((char*)&Bs[buf][0] + ldsOff0), 16, 0, 0);
    __builtin_amdgcn_global_load_lds((const AS1 void*)(gA1 + k0),
        (AS3 void*)((char*)&As[buf][0] + ldsOff1), 16, 0, 0);
    __builtin_amdgcn_global_load_lds((const AS1 void*)(gB1 + k0),
        (AS3 void*)((char*)&Bs[buf][0] + ldsOff1), 16, 0, 0);
  };

  int ck = (lk ^ (lr & 3)) * 8;
  auto compute = [&](int buf) {
    bf16x8 af[4], bfr[4];
    #pragma unroll
    for (int m = 0; m < 4; ++m)
      af[m] = *reinterpret_cast<const bf16x8*>(&As[buf][(wm * 64 + m * 16 + lr) * 32 + ck]);
    #pragma unroll
    for (int n = 0; n < 4; ++n)
      bfr[n] = *reinterpret_cast<const bf16x8*>(&Bs[buf][(wn * 64 + n * 16 + lr) * 32 + ck]);
    #pragma unroll
    for (int m = 0; m < 4; ++m)
      #pragma unroll
      for (int n = 0; n < 4; ++n)
        acc[m][n] = __builtin_amdgcn_mfma_f32_16x16x32_bf16(af[m], bfr[n], acc[m][n], 0, 0, 0);
  };

  int nsteps = K >> 5;
  stage(0, 0);
  stage(1, 32);
  int bt = 0;
  for (int t = 0; t < nsteps; ++t) {
    int rem = nsteps - 1 - t;
    if (rem >= 2) {
      int b2 = (bt == 0) ? 2 : bt - 1;
      stage(b2, (t + 2) << 5);
      asm volatile("s_waitcnt vmcnt(8)" ::: "memory");
    } else if (rem == 1) {
      asm volatile("s_waitcnt vmcnt(4)" ::: "memory");
    } else {
      asm volatile("s_waitcnt vmcnt(0)" ::: "memory");
    }
    __builtin_amdgcn_s_barrier();
    asm volatile("" ::: "memory");
    compute(bt);
    asm volatile("" ::: "memory");
    __builtin_amdgcn_s_barrier();
    bt = (bt == 2) ? 0 : bt + 1;
  }

  #pragma unroll
  for (int n = 0; n < 4; ++n) {
    int col = col0 + wn * 64 + n * 16 + lr;
    if (col >= N) continue;
    float bv = bias[col];
    #pragma unroll
    for (int m = 0; m < 4; ++m) {
      int rbase = row0 + wm * 64 + m * 16 + lk * 4;
      #pragma unroll
      for (int r2 = 0; r2 < 4; ++r2) {
        float v = acc[m][n][r2] + bv;
        if (EPI == 1) v = fast_gelu(v);
        int row = rbase + r2;
        if (EPI == 2)
          ((float*)Cp)[(size_t)row * N + col] = v;
        else if (EPI == 3)
          ((float*)Cp)[(size_t)row * N + col] += v;
        else
          ((u16*)Cp)[(size_t)row * N + col] = f2bf(v);
      }
    }
  }
}

// ---------------- V transpose: Vt[bh][d][k] = V[bh][k][d] ----------------
__global__ __launch_bounds__(256) void vtrans_k(const u16* __restrict__ qkv,
                                                u16* __restrict__ Vt) {
  int blk = blockIdx.x;
  int kt = blk & 7, bh = blk >> 3;
  int b = bh >> 4, h = bh & 15;
  __shared__ u16 t[64 * 66];
  int tid = threadIdx.x;
  #pragma unroll
  for (int i = 0; i < 16; ++i) {
    int idx = i * 256 + tid;
    int kk = idx >> 6, d = idx & 63;
    t[kk * 66 + d] = qkv[(size_t)(b * S_ + kt * 64 + kk) * 3072 + 2 * E_ + h * 64 + d];
  }
  __syncthreads();
  #pragma unroll
  for (int i = 0; i < 16; ++i) {
    int idx = i * 256 + tid;
    int d = idx >> 6, kk = idx & 63;
    Vt[(size_t)(bh * 64 + d) * S_ + kt * 64 + kk] = t[kk * 66 + d];
  }
}

// ---------------- fused QK^T + bias + mask + exp -> unnormalized P + invl ----------------
__global__ __launch_bounds__(256, 4) void attn_scores_k(const u16* __restrict__ qkv,
                                                        const int* __restrict__ dist,
                                                        const float* __restrict__ dist_emb,
                                                        const int* __restrict__ vseq,
                                                        u16* __restrict__ P,
                                                        float* __restrict__ invl) {
  int blk = blockIdx.x;
  int bh = blk & 127;
  int qt = blk >> 7;
  int b = bh >> 4, h = bh & 15;
  int tid = threadIdx.x, wv = tid >> 6, ln = tid & 63;
  int lr = ln & 15, lk = ln >> 4;

  __shared__ float de[208];
  __shared__ unsigned char padf[512];
  __shared__ unsigned char d8[64 * 512];

  int ncol = (qt + 1) * 64;
  for (int i = tid; i < 208; i += 256)
    de[i] = (i < 200) ? dist_emb[i * H_ + h] : -1e30f;
  for (int i = tid; i < (ncol >> 2); i += 256) {
    int4 v = *reinterpret_cast<const int4*>(vseq + b * S_ + i * 4);
    uchar4 pz;
    pz.x = (v.x == 0); pz.y = (v.y == 0); pz.z = (v.z == 0); pz.w = (v.w == 0);
    *reinterpret_cast<uchar4*>(&padf[i * 4]) = pz;
  }
  __syncthreads();

  {
    int r = tid >> 2;
    const int* drow = dist + ((size_t)(b * S_ + qt * 64 + r) << 9);
    int nc4 = ncol >> 2;
    for (int c4 = (tid & 3); c4 < nc4; c4 += 4) {
      int4 dv = *reinterpret_cast<const int4*>(drow + c4 * 4);
      uchar4 o;
      o.x = padf[c4 * 4 + 0] ? (unsigned char)200 : (unsigned char)dv.x;
      o.y = padf[c4 * 4 + 1] ? (unsigned char)200 : (unsigned char)dv.y;
      o.z = padf[c4 * 4 + 2] ? (unsigned char)200 : (unsigned char)dv.z;
      o.w = padf[c4 * 4 + 3] ? (unsigned char)200 : (unsigned char)dv.w;
      *reinterpret_cast<uchar4*>(&d8[(r << 9) + c4 * 4]) = o;
    }
  }
  __syncthreads();

  int q0 = qt * 64 + wv * 16;
  int nv = 4 * qt + wv + 1;
  int nreq = 4 * qt + 2 * (wv >> 1) + 2;
  int qrow = q0 + lk * 4;
  int lrow = wv * 16 + lk * 4;

  bf16x8 aq0 = *reinterpret_cast<const bf16x8*>(
      qkv + (size_t)(b * S_ + q0 + lr) * 3072 + h * 64 + lk * 8);
  bf16x8 aq1 = *reinterpret_cast<const bf16x8*>(
      qkv + (size_t)(b * S_ + q0 + lr) * 3072 + h * 64 + 32 + lk * 8);

  float sm[4] = {0.f, 0.f, 0.f, 0.f};
  f32x4 z = {0.f, 0.f, 0.f, 0.f};
  int nch = (nv + 3) >> 2;
  #pragma unroll 1
  for (int c = 0; c < nch; ++c) {
    int base = c * 4;
    f32x4 acc[4] = {z, z, z, z};
    #pragma unroll
    for (int j = 0; j < 4; ++j) {
      int n = base + j;
      if (n < nv) {
        const u16* kb = qkv + (size_t)(b * S_ + n * 16 + lr) * 3072 + E_ + h * 64 + lk * 8;
        bf16x8 bk0 = *reinterpret_cast<const bf16x8*>(kb);
        bf16x8 bk1 = *reinterpret_cast<const bf16x8*>(kb + 32);
        acc[j] = __builtin_amdgcn_mfma_f32_16x16x32_bf16(aq0, bk0, acc[j], 0, 0, 0);
        acc[j] = __builtin_amdgcn_mfma_f32_16x16x32_bf16(aq1, bk1, acc[j], 0, 0, 0);
      }
    }
    #pragma unroll
    for (int j = 0; j < 4; ++j) {
      int n = base + j;
      if (n < nv) {
        int col = n * 16 + lr;
        #pragma unroll
        for (int r2 = 0; r2 < 4; ++r2) {
          float e = 0.f;
          if (col <= qrow + r2) {
            int d = d8[((lrow + r2) << 9) + col];
            e = __expf(acc[j][r2] * 0.125f + de[d]);
          }
          sm[r2] += e;
          P[(size_t)(bh * S_ + qrow + r2) * S_ + col] = f2bf(e);
        }
      }
    }
  }
  for (int n = nv; n < nreq; ++n) {
    int col = n * 16 + lr;
    #pragma unroll
    for (int r2 = 0; r2 < 4; ++r2)
      P[(size_t)(bh * S_ + qrow + r2) * S_ + col] = 0;
  }
  #pragma unroll
  for (int off = 1; off < 16; off <<= 1)
    #pragma unroll
    for (int r2 = 0; r2 < 4; ++r2) sm[r2] += __shfl_xor(sm[r2], off, 64);
  if (lr == 0) {
    #pragma unroll
    for (int r2 = 0; r2 < 4; ++r2)
      invl[bh * S_ + qrow + r2] = 1.f / sm[r2];
  }
}

// ---------------- ctx = (P @ V) * invl (via Vt) ----------------
__global__ __launch_bounds__(256) void attn_pv_k(const u16* __restrict__ P,
                                                 const u16* __restrict__ Vt,
                                                 const float* __restrict__ invl,
                                                 u16* __restrict__ ctx) {
  int blk = blockIdx.x;
  int mt = blk & 3, bh = blk >> 2;
  int b = bh >> 4, h = bh & 15;
  int tid = threadIdx.x, wv = tid >> 6, ln = tid & 63;
  int lr = ln & 15, lk = ln >> 4;
  int r0 = mt * 128 + wv * 32;
  f32x4 acc[2][4];
  f32x4 z = {0.f, 0.f, 0.f, 0.f};
  #pragma unroll
  for (int m = 0; m < 2; ++m)
    #pragma unroll
    for (int n = 0; n < 4; ++n) acc[m][n] = z;
  int nks = mt * 4 + wv + 1;
  for (int ks = 0; ks < nks; ++ks) {
    int k0 = ks * 32;
    bf16x8 ap[2];
    #pragma unroll
    for (int m = 0; m < 2; ++m)
      ap[m] = *reinterpret_cast<const bf16x8*>(
          P + (size_t)(bh * S_ + r0 + m * 16 + lr) * S_ + k0 + lk * 8);
    #pragma unroll
    for (int n = 0; n < 4; ++n) {
      bf16x8 bv = *reinterpret_cast<const bf16x8*>(
          Vt + (size_t)(bh * 64 + n * 16 + lr) * S_ + k0 + lk * 8);
      #pragma unroll
      for (int m = 0; m < 2; ++m)
        acc[m][n] = __builtin_amdgcn_mfma_f32_16x16x32_bf16(ap[m], bv, acc[m][n], 0, 0, 0);
    }
  }
  float il[2][4];
  #pragma unroll
  for (int m = 0; m < 2; ++m)
    #pragma unroll
    for (int r = 0; r < 4; ++r)
      il[m][r] = invl[bh * S_ + r0 + m * 16 + lk * 4 + r];
  #pragma unroll
  for (int m = 0; m < 2; ++m)
    #pragma unroll
    for (int n = 0; n < 4; ++n)
      #pragma unroll
      for (int r = 0; r < 4; ++r) {
        int row = r0 + m * 16 + lk * 4 + r;
        int col = n * 16 + lr;
        ctx[(size_t)(b * S_ + row) * E_ + h * 64 + col] = f2bf(acc[m][n][r] * il[m][r]);
      }
}

extern "C" void kernel_launch(void* const* d_in, const int* in_sizes, int n_in,
                              void* d_out, int out_size, void* d_ws, size_t ws_size,
                              hipStream_t stream) {
  const float* val_emb = (const float*)d_in[0];
  const float* ring_emb = (const float*)d_in[1];
  const float* dist_emb = (const float*)d_in[2];
  const float* Wqkv = (const float*)d_in[3];
  const float* bqkv = (const float*)d_in[4];
  const float* Wo = (const float*)d_in[5];
  const float* bo = (const float*)d_in[6];
  const float* ln1_s = (const float*)d_in[7];
  const float* ln1_b = (const float*)d_in[8];
  const float* W1 = (const float*)d_in[9];
  const float* b1 = (const float*)d_in[10];
  const float* W2 = (const float*)d_in[11];
  const float* b2 = (const float*)d_in[12];
  const float* ln2_s = (const float*)d_in[13];
  const float* ln2_b = (const float*)d_in[14];
  const float* lnf_s = (const float*)d_in[15];
  const float* lnf_b = (const float*)d_in[16];
  const float* gen_W = (const float*)d_in[17];
  const float* gen_b = (const float*)d_in[18];
  const int* vseq = (const int*)d_in[19];
  const int* rseq = (const int*)d_in[20];
  const int* dist = (const int*)d_in[21];

  char* ws = (char*)d_ws;
  size_t off = 0;
  auto alloc = [&](size_t nbytes) {
    char* p = ws + off;
    off += (nbytes + 255) & ~(size_t)255;
    return p;
  };
  u16* gw_bf = (u16*)alloc((size_t)GEN_N * E_ * 2);
  u16* wqkv_l = (u16*)alloc((size_t)3 * E_ * E_ * 2);
  u16* wo_l = (u16*)alloc((size_t)E_ * E_ * 2);
  u16* w1_l = (u16*)alloc((size_t)F_ * E_ * 2);
  u16* w2_l = (u16*)alloc((size_t)E_ * F_ * 2);
  float* h = (float*)alloc((size_t)T_ * E_ * 4);
  u16* x_bf = (u16*)alloc((size_t)T_ * E_ * 2);
  u16* qkv_bf = (u16*)alloc((size_t)T_ * 3 * E_ * 2);
  u16* ctx_bf = (u16*)alloc((size_t)T_ * E_ * 2);
  u16* vt_bf = (u16*)alloc((size_t)B_ * H_ * 64 * S_ * 2);
  float* invl = (float*)alloc((size_t)B_ * H_ * S_ * 4);
  u16* p_bf = (u16*)alloc((size_t)B_ * H_ * S_ * S_ * 2);
  u16* ff_bf = p_bf;  // aliased: P dead before FF is produced
  (void)ws_size; (void)in_sizes; (void)n_in; (void)out_size; (void)rseq;

  auto cvt = [&](const float* s, u16* d, int n) {
    cvt_bf16<<<dim3((n / 4 + 255) / 256), dim3(256), 0, stream>>>(s, d, n);
  };
  cvt(gen_W, gw_bf, GEN_N * E_);

  embed_k<<<dim3(T_), dim3(256), 0, stream>>>(val_emb, ring_emb, vseq, rseq, h, x_bf);

  for (int l = 0; l < L_; ++l) {
    cvt(Wqkv + (size_t)l * 3 * E_ * E_, wqkv_l, 3 * E_ * E_);
    cvt(Wo + (size_t)l * E_ * E_, wo_l, E_ * E_);
    cvt(W1 + (size_t)l * F_ * E_, w1_l, F_ * E_);
    cvt(W2 + (size_t)l * E_ * F_, w2_l, E_ * F_);

    gemm256<0><<<dim3(192), dim3(512), 0, stream>>>(
        x_bf, wqkv_l, bqkv + (size_t)l * 3 * E_, qkv_bf, T_, 3 * E_, E_, 12);
    vtrans_k<<<dim3(B_ * H_ * 8), dim3(256), 0, stream>>>(qkv_bf, vt_bf);
    attn_scores_k<<<dim3(B_ * H_ * 8), dim3(256), 0, stream>>>(qkv_bf, dist, dist_emb, vseq,
                                                               p_bf, invl);
    attn_pv_k<<<dim3(B_ * H_ * 4), dim3(256), 0, stream>>>(p_bf, vt_bf, invl, ctx_bf);
    gemm_bt<3><<<dim3(32 * 8), dim3(256), 0, stream>>>(
        ctx_bf, wo_l, bo + (size_t)l * E_, h, T_, E_, E_, 8);
    ln_k<<<dim3(T_), dim3(256), 0, stream>>>(h, ln1_s + (size_t)l * E_,
                                             ln1_b + (size_t)l * E_, h, x_bf);
    gemm256<1><<<dim3(256), dim3(512), 0, stream>>>(
        x_bf, w1_l, b1 + (size_t)l * F_, ff_bf, T_, F_, E_, 16);
    gemm_bt<3><<<dim3(32 * 8), dim3(256), 0, stream>>>(
        ff_bf, w2_l, b2 + (size_t)l * E_, h, T_, E_, F_, 8);
    ln_k<<<dim3(T_), dim3(256), 0, stream>>>(h, ln2_s + (size_t)l * E_,
                                             ln2_b + (size_t)l * E_, h, x_bf);
  }
  ln_k<<<dim3(T_), dim3(256), 0, stream>>>(h, lnf_s, lnf_b, nullptr, x_bf);
  gemm_bt<2><<<dim3(32 * 10), dim3(256), 0, stream>>>(
      x_bf, gw_bf, gen_b, (float*)d_out, T_, GEN_N, E_, 10);
}

// Round 9
// 1160.515 us; speedup vs baseline: 1.2352x; 1.1495x over previous
//
#include <hip/hip_runtime.h>
#include <hip/hip_bf16.h>

typedef __attribute__((ext_vector_type(8))) short bf16x8;
typedef __attribute__((ext_vector_type(4))) float f32x4;
typedef unsigned short u16;
typedef __attribute__((ext_vector_type(4))) unsigned short u16x4;

#define L_ 4
#define E_ 1024
#define H_ 16
#define F_ 4096
#define B_ 8
#define S_ 512
#define T_ 4096
#define GEN_N 1200

#define AS1 __attribute__((address_space(1)))
#define AS3 __attribute__((address_space(3)))

static __device__ __forceinline__ u16 f2bf(float f) {
  unsigned u = __float_as_uint(f);
  unsigned r = (u + 0x7fffu + ((u >> 16) & 1u)) >> 16;
  return (u16)r;
}

static __device__ __forceinline__ float fast_gelu(float v) {
  float y = 0.7978845608f * (v + 0.044715f * v * v * v);
  y = fminf(fmaxf(y, -9.f), 9.f);
  float e2 = __expf(2.f * y);
  float th = (e2 - 1.f) / (e2 + 1.f);
  return 0.5f * v * (1.f + th);
}

// ---------------- f32 -> bf16 convert ----------------
__global__ __launch_bounds__(256) void cvt_bf16(const float* __restrict__ src,
                                                u16* __restrict__ dst, int n) {
  int i = (blockIdx.x * 256 + threadIdx.x) * 4;
  if (i >= n) return;
  float4 v = *reinterpret_cast<const float4*>(src + i);
  u16x4 o = {f2bf(v.x), f2bf(v.y), f2bf(v.z), f2bf(v.w)};
  *reinterpret_cast<u16x4*>(dst + i) = o;
}

// ---------------- embedding ----------------
__global__ __launch_bounds__(256) void embed_k(const float* __restrict__ val_emb,
                                               const float* __restrict__ ring_emb,
                                               const int* __restrict__ vseq,
                                               const int* __restrict__ rseq,
                                               float* __restrict__ h, u16* __restrict__ xbf) {
  int tok = blockIdx.x;
  int e = threadIdx.x * 4;
  int v = vseq[tok], r = rseq[tok];
  float4 a = *reinterpret_cast<const float4*>(val_emb + v * E_ + e);
  float4 b = *reinterpret_cast<const float4*>(ring_emb + r * E_ + e);
  float4 o;
  o.x = (a.x + b.x) * 32.f; o.y = (a.y + b.y) * 32.f;
  o.z = (a.z + b.z) * 32.f; o.w = (a.w + b.w) * 32.f;
  *reinterpret_cast<float4*>(h + (size_t)tok * E_ + e) = o;
  u16x4 ob = {f2bf(o.x), f2bf(o.y), f2bf(o.z), f2bf(o.w)};
  *reinterpret_cast<u16x4*>(xbf + (size_t)tok * E_ + e) = ob;
}

// ---------------- LayerNorm (v = h [+ add0 + add1 + cbias]) ----------------
__global__ __launch_bounds__(256) void ln_k(const float* hin, const float* add0,
                                            const float* add1, const float* cbias,
                                            const float* g, const float* bta,
                                            float* hout, u16* xout) {
  int tok = blockIdx.x;
  int e = threadIdx.x * 4;
  float4 v = *reinterpret_cast<const float4*>(hin + (size_t)tok * E_ + e);
  if (add0) {
    float4 a0 = *reinterpret_cast<const float4*>(add0 + (size_t)tok * E_ + e);
    float4 a1 = *reinterpret_cast<const float4*>(add1 + (size_t)tok * E_ + e);
    float4 cb = *reinterpret_cast<const float4*>(cbias + e);
    v.x += a0.x + a1.x + cb.x; v.y += a0.y + a1.y + cb.y;
    v.z += a0.z + a1.z + cb.z; v.w += a0.w + a1.w + cb.w;
  }
  float s = v.x + v.y + v.z + v.w;
  float q = v.x * v.x + v.y * v.y + v.z * v.z + v.w * v.w;
  #pragma unroll
  for (int off = 1; off < 64; off <<= 1) {
    s += __shfl_xor(s, off, 64);
    q += __shfl_xor(q, off, 64);
  }
  __shared__ float ls[4], lq[4];
  int wv = threadIdx.x >> 6, ln = threadIdx.x & 63;
  if (ln == 0) { ls[wv] = s; lq[wv] = q; }
  __syncthreads();
  s = ls[0] + ls[1] + ls[2] + ls[3];
  q = lq[0] + lq[1] + lq[2] + lq[3];
  float mean = s * (1.f / E_);
  float var = q * (1.f / E_) - mean * mean;
  float inv = rsqrtf(var + 1e-5f);
  float4 gg = *reinterpret_cast<const float4*>(g + e);
  float4 bb = *reinterpret_cast<const float4*>(bta + e);
  float4 o;
  o.x = (v.x - mean) * inv * gg.x + bb.x;
  o.y = (v.y - mean) * inv * gg.y + bb.y;
  o.z = (v.z - mean) * inv * gg.z + bb.z;
  o.w = (v.w - mean) * inv * gg.w + bb.w;
  if (hout) *reinterpret_cast<float4*>(hout + (size_t)tok * E_ + e) = o;
  u16x4 ob = {f2bf(o.x), f2bf(o.y), f2bf(o.z), f2bf(o.w)};
  *reinterpret_cast<u16x4*>(xout + (size_t)tok * E_ + e) = ob;
}

// ---------------- big-tile GEMM: C = A[M,K] @ W[N,K]^T (+bias) ----------------
// BM=256, BN=64*NW, 512 thr = 8 waves (2M x 4N), per-wave 128 x 16*NW, BK=64.
// Counted vmcnt across raw barriers; both-sides XOR swizzle (chunk ^= row&7).
// EPI: 0 = bf16 out +bias, 1 = gelu(bf16) +bias, 2 = raw f32 partial (split-K)
template <int EPI, int NW, int SPLITK>
__global__ __launch_bounds__(512, 2) void gemm_big(const u16* __restrict__ A,
                                                   const u16* __restrict__ W,
                                                   const float* __restrict__ bias,
                                                   void* __restrict__ Cp,
                                                   int M, int N, int K, int tilesN) {
  constexpr int BN = 64 * NW;
  __shared__ __align__(16) u16 As[2][256 * 64];
  __shared__ __align__(16) u16 Bs[2][BN * 64];
  int tid = threadIdx.x;
  int wid = tid >> 6, ln = tid & 63;
  int wm = wid >> 2, wn = wid & 3;
  int lr = ln & 15, lk = ln >> 4;
  int nwg = gridDim.x;
  int bid = blockIdx.x;
  int swz = ((nwg & 7) == 0) ? ((bid & 7) * (nwg >> 3) + (bid >> 3)) : bid;
  int sp = 0, tile = swz;
  if (SPLITK > 1) { sp = swz & (SPLITK - 1); tile = swz / SPLITK; }
  int tm = tile / tilesN, tn = tile % tilesN;
  int row0 = tm * 256, col0 = tn * BN;
  int Ks = K / SPLITK;
  int kbase = sp * Ks;

  // staging: thread -> row (tid>>3) within 64-row pass, chunk (tid&7) ^ row&7
  int srow = tid >> 3;
  int schunk = ((tid & 7) ^ (srow & 7)) * 8;
  const u16* gA = A + (size_t)(row0 + srow) * K + kbase + schunk;
  const u16* gB = W + (size_t)(col0 + srow) * K + kbase + schunk;
  size_t ldsBase = (size_t)((wid << 3) * 64) * 2;  // bytes

  auto stage = [&](int buf, int kt) {
    size_t ko = (size_t)kt * 64;
    #pragma unroll
    for (int i = 0; i < 4; ++i)
      __builtin_amdgcn_global_load_lds(
          (const AS1 void*)(gA + (size_t)i * 64 * K + ko),
          (AS3 void*)((char*)&As[buf][0] + ldsBase + (size_t)i * 64 * 128), 16, 0, 0);
    #pragma unroll
    for (int i = 0; i < NW; ++i)
      __builtin_amdgcn_global_load_lds(
          (const AS1 void*)(gB + (size_t)i * 64 * K + ko),
          (AS3 void*)((char*)&Bs[buf][0] + ldsBase + (size_t)i * 64 * 128), 16, 0, 0);
  };

  f32x4 acc[8][NW];
  f32x4 z = {0.f, 0.f, 0.f, 0.f};
  #pragma unroll
  for (int m = 0; m < 8; ++m)
    #pragma unroll
    for (int n = 0; n < NW; ++n) acc[m][n] = z;

  auto compute = [&](int buf) {
    #pragma unroll
    for (int s = 0; s < 2; ++s) {
      int ch = ((s * 4 + lk) ^ (lr & 7)) * 8;
      bf16x8 bfr[NW];
      #pragma unroll
      for (int n = 0; n < NW; ++n)
        bfr[n] = *reinterpret_cast<const bf16x8*>(&Bs[buf][(wn * (16 * NW) + n * 16 + lr) * 64 + ch]);
      #pragma unroll
      for (int m = 0; m < 8; ++m) {
        bf16x8 af = *reinterpret_cast<const bf16x8*>(&As[buf][(wm * 128 + m * 16 + lr) * 64 + ch]);
        #pragma unroll
        for (int n = 0; n < NW; ++n)
          acc[m][n] = __builtin_amdgcn_mfma_f32_16x16x32_bf16(af, bfr[n], acc[m][n], 0, 0, 0);
      }
    }
  };

  int nt = Ks >> 6;
  stage(0, 0);
  int cur = 0;
  for (int t = 0; t < nt; ++t) {
    if (t + 1 < nt) {
      stage(cur ^ 1, t + 1);
      if constexpr (NW == 2) asm volatile("s_waitcnt vmcnt(6)" ::: "memory");
      else if constexpr (NW == 3) asm volatile("s_waitcnt vmcnt(7)" ::: "memory");
      else asm volatile("s_waitcnt vmcnt(8)" ::: "memory");
    } else {
      asm volatile("s_waitcnt vmcnt(0)" ::: "memory");
    }
    __builtin_amdgcn_s_barrier();
    asm volatile("" ::: "memory");
    compute(cur);
    asm volatile("" ::: "memory");
    __builtin_amdgcn_s_barrier();
    cur ^= 1;
  }

  #pragma unroll
  for (int n = 0; n < NW; ++n) {
    int col = col0 + wn * (16 * NW) + n * 16 + lr;
    float bv = (EPI == 2) ? 0.f : bias[col];
    #pragma unroll
    for (int m = 0; m < 8; ++m) {
      int rbase = row0 + wm * 128 + m * 16 + lk * 4;
      #pragma unroll
      for (int r2 = 0; r2 < 4; ++r2) {
        float v = acc[m][n][r2] + bv;
        if (EPI == 1) v = fast_gelu(v);
        if (EPI == 2)
          ((float*)Cp)[(size_t)sp * M * N + (size_t)(rbase + r2) * N + col] = v;
        else
          ((u16*)Cp)[(size_t)(rbase + r2) * N + col] = f2bf(v);
      }
    }
  }
}

// ---------------- 128x128 GEMM (Wo / gen) ----------------
// EPI: 2 = f32 out, 3 = f32 accumulate
template <int EPI>
__global__ __launch_bounds__(256) void gemm_bt(const u16* __restrict__ A,
                                               const u16* __restrict__ W,
                                               const float* __restrict__ bias,
                                               void* __restrict__ Cp,
                                               int M, int N, int K, int tilesN) {
  __shared__ __align__(16) u16 As[3][128 * 32];
  __shared__ __align__(16) u16 Bs[3][128 * 32];
  int tid = threadIdx.x;
  int wv = tid >> 6, ln = tid & 63;
  int wm = wv >> 1, wn = wv & 1;
  int nwg = gridDim.x;
  int bid = blockIdx.x;
  int swz = ((nwg & 7) == 0) ? ((bid & 7) * (nwg >> 3) + (bid >> 3)) : bid;
  int tm = swz / tilesN, tn = swz % tilesN;
  int row0 = tm * 128, col0 = tn * 128;
  int lr = ln & 15, lk = ln >> 4;

  f32x4 acc[4][4];
  f32x4 z = {0.f, 0.f, 0.f, 0.f};
  #pragma unroll
  for (int m = 0; m < 4; ++m)
    #pragma unroll
    for (int n = 0; n < 4; ++n) acc[m][n] = z;

  int srow = tid >> 2;
  int scol = ((tid & 3) ^ (srow & 3)) * 8;
  const u16* gA0 = A + (size_t)(row0 + srow) * K + scol;
  const u16* gA1 = A + (size_t)(row0 + 64 + srow) * K + scol;
  int wr0 = col0 + srow;      if (wr0 >= N) wr0 = N - 1;
  int wr1 = col0 + 64 + srow; if (wr1 >= N) wr1 = N - 1;
  const u16* gB0 = W + (size_t)wr0 * K + scol;
  const u16* gB1 = W + (size_t)wr1 * K + scol;
  size_t ldsOff0 = (size_t)(wv << 6) * 16;
  size_t ldsOff1 = (size_t)(256 + (wv << 6)) * 16;

  auto stage = [&](int buf, int k0) {
    __builtin_amdgcn_global_load_lds((const AS1 void*)(gA0 + k0),
        (AS3 void*)((char*)&As[buf][0] + ldsOff0), 16, 0, 0);
    __builtin_amdgcn_global_load_lds((const AS1 void*)(gB0 + k0),
        (AS3 void*)((char*)&Bs[buf][0] + ldsOff0), 16, 0, 0);
    __builtin_amdgcn_global_load_lds((const AS1 void*)(gA1 + k0),
        (AS3 void*)((char*)&As[buf][0] + ldsOff1), 16, 0, 0);
    __builtin_amdgcn_global_load_lds((const AS1 void*)(gB1 + k0),
        (AS3 void*)((char*)&Bs[buf][0] + ldsOff1), 16, 0, 0);
  };

  int ck = (lk ^ (lr & 3)) * 8;
  auto compute = [&](int buf) {
    bf16x8 af[4], bfr[4];
    #pragma unroll
    for (int m = 0; m < 4; ++m)
      af[m] = *reinterpret_cast<const bf16x8*>(&As[buf][(wm * 64 + m * 16 + lr) * 32 + ck]);
    #pragma unroll
    for (int n = 0; n < 4; ++n)
      bfr[n] = *reinterpret_cast<const bf16x8*>(&Bs[buf][(wn * 64 + n * 16 + lr) * 32 + ck]);
    #pragma unroll
    for (int m = 0; m < 4; ++m)
      #pragma unroll
      for (int n = 0; n < 4; ++n)
        acc[m][n] = __builtin_amdgcn_mfma_f32_16x16x32_bf16(af[m], bfr[n], acc[m][n], 0, 0, 0);
  };

  int nsteps = K >> 5;
  stage(0, 0);
  stage(1, 32);
  int bt = 0;
  for (int t = 0; t < nsteps; ++t) {
    int rem = nsteps - 1 - t;
    if (rem >= 2) {
      int b2 = (bt == 0) ? 2 : bt - 1;
      stage(b2, (t + 2) << 5);
      asm volatile("s_waitcnt vmcnt(8)" ::: "memory");
    } else if (rem == 1) {
      asm volatile("s_waitcnt vmcnt(4)" ::: "memory");
    } else {
      asm volatile("s_waitcnt vmcnt(0)" ::: "memory");
    }
    __builtin_amdgcn_s_barrier();
    asm volatile("" ::: "memory");
    compute(bt);
    asm volatile("" ::: "memory");
    __builtin_amdgcn_s_barrier();
    bt = (bt == 2) ? 0 : bt + 1;
  }

  #pragma unroll
  for (int n = 0; n < 4; ++n) {
    int col = col0 + wn * 64 + n * 16 + lr;
    if (col >= N) continue;
    float bv = bias[col];
    #pragma unroll
    for (int m = 0; m < 4; ++m) {
      int rbase = row0 + wm * 64 + m * 16 + lk * 4;
      #pragma unroll
      for (int r2 = 0; r2 < 4; ++r2) {
        float v = acc[m][n][r2] + bv;
        int row = rbase + r2;
        if (EPI == 2)
          ((float*)Cp)[(size_t)row * N + col] = v;
        else
          ((float*)Cp)[(size_t)row * N + col] += v;
      }
    }
  }
}

// ---------------- V transpose: Vt[bh][d][k] = V[bh][k][d] ----------------
__global__ __launch_bounds__(256) void vtrans_k(const u16* __restrict__ qkv,
                                                u16* __restrict__ Vt) {
  int blk = blockIdx.x;
  int kt = blk & 7, bh = blk >> 3;
  int b = bh >> 4, h = bh & 15;
  __shared__ u16 t[64 * 66];
  int tid = threadIdx.x;
  #pragma unroll
  for (int i = 0; i < 16; ++i) {
    int idx = i * 256 + tid;
    int kk = idx >> 6, d = idx & 63;
    t[kk * 66 + d] = qkv[(size_t)(b * S_ + kt * 64 + kk) * 3072 + 2 * E_ + h * 64 + d];
  }
  __syncthreads();
  #pragma unroll
  for (int i = 0; i < 16; ++i) {
    int idx = i * 256 + tid;
    int d = idx >> 6, kk = idx & 63;
    Vt[(size_t)(bh * 64 + d) * S_ + kt * 64 + kk] = t[kk * 66 + d];
  }
}

// ---------------- fused QK^T + bias + mask + exp -> unnormalized P + invl ----------------
__global__ __launch_bounds__(256, 4) void attn_scores_k(const u16* __restrict__ qkv,
                                                        const int* __restrict__ dist,
                                                        const float* __restrict__ dist_emb,
                                                        const int* __restrict__ vseq,
                                                        u16* __restrict__ P,
                                                        float* __restrict__ invl) {
  int blk = blockIdx.x;
  int bh = blk & 127;
  int qt = blk >> 7;
  int b = bh >> 4, h = bh & 15;
  int tid = threadIdx.x, wv = tid >> 6, ln = tid & 63;
  int lr = ln & 15, lk = ln >> 4;

  __shared__ float de[208];
  __shared__ unsigned char padf[512];
  __shared__ unsigned char d8[64 * 512];

  int ncol = (qt + 1) * 64;
  for (int i = tid; i < 208; i += 256)
    de[i] = (i < 200) ? dist_emb[i * H_ + h] : -1e30f;
  for (int i = tid; i < (ncol >> 2); i += 256) {
    int4 v = *reinterpret_cast<const int4*>(vseq + b * S_ + i * 4);
    uchar4 pz;
    pz.x = (v.x == 0); pz.y = (v.y == 0); pz.z = (v.z == 0); pz.w = (v.w == 0);
    *reinterpret_cast<uchar4*>(&padf[i * 4]) = pz;
  }
  __syncthreads();

  {
    int r = tid >> 2;
    const int* drow = dist + ((size_t)(b * S_ + qt * 64 + r) << 9);
    int nc4 = ncol >> 2;
    for (int c4 = (tid & 3); c4 < nc4; c4 += 4) {
      int4 dv = *reinterpret_cast<const int4*>(drow + c4 * 4);
      uchar4 o;
      o.x = padf[c4 * 4 + 0] ? (unsigned char)200 : (unsigned char)dv.x;
      o.y = padf[c4 * 4 + 1] ? (unsigned char)200 : (unsigned char)dv.y;
      o.z = padf[c4 * 4 + 2] ? (unsigned char)200 : (unsigned char)dv.z;
      o.w = padf[c4 * 4 + 3] ? (unsigned char)200 : (unsigned char)dv.w;
      *reinterpret_cast<uchar4*>(&d8[(r << 9) + c4 * 4]) = o;
    }
  }
  __syncthreads();

  int q0 = qt * 64 + wv * 16;
  int nv = 4 * qt + wv + 1;
  int nreq = 4 * qt + 2 * (wv >> 1) + 2;
  int qrow = q0 + lk * 4;
  int lrow = wv * 16 + lk * 4;

  bf16x8 aq0 = *reinterpret_cast<const bf16x8*>(
      qkv + (size_t)(b * S_ + q0 + lr) * 3072 + h * 64 + lk * 8);
  bf16x8 aq1 = *reinterpret_cast<const bf16x8*>(
      qkv + (size_t)(b * S_ + q0 + lr) * 3072 + h * 64 + 32 + lk * 8);

  float sm[4] = {0.f, 0.f, 0.f, 0.f};
  f32x4 z = {0.f, 0.f, 0.f, 0.f};
  int nch = (nv + 3) >> 2;
  #pragma unroll 1
  for (int c = 0; c < nch; ++c) {
    int base = c * 4;
    f32x4 acc[4] = {z, z, z, z};
    #pragma unroll
    for (int j = 0; j < 4; ++j) {
      int n = base + j;
      if (n < nv) {
        const u16* kb = qkv + (size_t)(b * S_ + n * 16 + lr) * 3072 + E_ + h * 64 + lk * 8;
        bf16x8 bk0 = *reinterpret_cast<const bf16x8*>(kb);
        bf16x8 bk1 = *reinterpret_cast<const bf16x8*>(kb + 32);
        acc[j] = __builtin_amdgcn_mfma_f32_16x16x32_bf16(aq0, bk0, acc[j], 0, 0, 0);
        acc[j] = __builtin_amdgcn_mfma_f32_16x16x32_bf16(aq1, bk1, acc[j], 0, 0, 0);
      }
    }
    #pragma unroll
    for (int j = 0; j < 4; ++j) {
      int n = base + j;
      if (n < nv) {
        int col = n * 16 + lr;
        #pragma unroll
        for (int r2 = 0; r2 < 4; ++r2) {
          float e = 0.f;
          if (col <= qrow + r2) {
            int d = d8[((lrow + r2) << 9) + col];
            e = __expf(acc[j][r2] * 0.125f + de[d]);
          }
          sm[r2] += e;
          P[(size_t)(bh * S_ + qrow + r2) * S_ + col] = f2bf(e);
        }
      }
    }
  }
  for (int n = nv; n < nreq; ++n) {
    int col = n * 16 + lr;
    #pragma unroll
    for (int r2 = 0; r2 < 4; ++r2)
      P[(size_t)(bh * S_ + qrow + r2) * S_ + col] = 0;
  }
  #pragma unroll
  for (int off = 1; off < 16; off <<= 1)
    #pragma unroll
    for (int r2 = 0; r2 < 4; ++r2) sm[r2] += __shfl_xor(sm[r2], off, 64);
  if (lr == 0) {
    #pragma unroll
    for (int r2 = 0; r2 < 4; ++r2)
      invl[bh * S_ + qrow + r2] = 1.f / sm[r2];
  }
}

// ---------------- ctx = (P @ V) * invl (via Vt) ----------------
__global__ __launch_bounds__(256) void attn_pv_k(const u16* __restrict__ P,
                                                 const u16* __restrict__ Vt,
                                                 const float* __restrict__ invl,
                                                 u16* __restrict__ ctx) {
  int blk = blockIdx.x;
  int mt = blk & 3, bh = blk >> 2;
  int b = bh >> 4, h = bh & 15;
  int tid = threadIdx.x, wv = tid >> 6, ln = tid & 63;
  int lr = ln & 15, lk = ln >> 4;
  int r0 = mt * 128 + wv * 32;
  f32x4 acc[2][4];
  f32x4 z = {0.f, 0.f, 0.f, 0.f};
  #pragma unroll
  for (int m = 0; m < 2; ++m)
    #pragma unroll
    for (int n = 0; n < 4; ++n) acc[m][n] = z;
  int nks = mt * 4 + wv + 1;
  for (int ks = 0; ks < nks; ++ks) {
    int k0 = ks * 32;
    bf16x8 ap[2];
    #pragma unroll
    for (int m = 0; m < 2; ++m)
      ap[m] = *reinterpret_cast<const bf16x8*>(
          P + (size_t)(bh * S_ + r0 + m * 16 + lr) * S_ + k0 + lk * 8);
    #pragma unroll
    for (int n = 0; n < 4; ++n) {
      bf16x8 bv = *reinterpret_cast<const bf16x8*>(
          Vt + (size_t)(bh * 64 + n * 16 + lr) * S_ + k0 + lk * 8);
      #pragma unroll
      for (int m = 0; m < 2; ++m)
        acc[m][n] = __builtin_amdgcn_mfma_f32_16x16x32_bf16(ap[m], bv, acc[m][n], 0, 0, 0);
    }
  }
  float il[2][4];
  #pragma unroll
  for (int m = 0; m < 2; ++m)
    #pragma unroll
    for (int r = 0; r < 4; ++r)
      il[m][r] = invl[bh * S_ + r0 + m * 16 + lk * 4 + r];
  #pragma unroll
  for (int m = 0; m < 2; ++m)
    #pragma unroll
    for (int n = 0; n < 4; ++n)
      #pragma unroll
      for (int r = 0; r < 4; ++r) {
        int row = r0 + m * 16 + lk * 4 + r;
        int col = n * 16 + lr;
        ctx[(size_t)(b * S_ + row) * E_ + h * 64 + col] = f2bf(acc[m][n][r] * il[m][r]);
      }
}

extern "C" void kernel_launch(void* const* d_in, const int* in_sizes, int n_in,
                              void* d_out, int out_size, void* d_ws, size_t ws_size,
                              hipStream_t stream) {
  const float* val_emb = (const float*)d_in[0];
  const float* ring_emb = (const float*)d_in[1];
  const float* dist_emb = (const float*)d_in[2];
  const float* Wqkv = (const float*)d_in[3];
  const float* bqkv = (const float*)d_in[4];
  const float* Wo = (const float*)d_in[5];
  const float* bo = (const float*)d_in[6];
  const float* ln1_s = (const float*)d_in[7];
  const float* ln1_b = (const float*)d_in[8];
  const float* W1 = (const float*)d_in[9];
  const float* b1 = (const float*)d_in[10];
  const float* W2 = (const float*)d_in[11];
  const float* b2 = (const float*)d_in[12];
  const float* ln2_s = (const float*)d_in[13];
  const float* ln2_b = (const float*)d_in[14];
  const float* lnf_s = (const float*)d_in[15];
  const float* lnf_b = (const float*)d_in[16];
  const float* gen_W = (const float*)d_in[17];
  const float* gen_b = (const float*)d_in[18];
  const int* vseq = (const int*)d_in[19];
  const int* rseq = (const int*)d_in[20];
  const int* dist = (const int*)d_in[21];

  char* ws = (char*)d_ws;
  size_t off = 0;
  auto alloc = [&](size_t nbytes) {
    char* p = ws + off;
    off += (nbytes + 255) & ~(size_t)255;
    return p;
  };
  u16* gw_bf = (u16*)alloc((size_t)GEN_N * E_ * 2);
  u16* wqkv_l = (u16*)alloc((size_t)3 * E_ * E_ * 2);
  u16* wo_l = (u16*)alloc((size_t)E_ * E_ * 2);
  u16* w1_l = (u16*)alloc((size_t)F_ * E_ * 2);
  u16* w2_l = (u16*)alloc((size_t)E_ * F_ * 2);
  float* h = (float*)alloc((size_t)T_ * E_ * 4);
  u16* x_bf = (u16*)alloc((size_t)T_ * E_ * 2);
  u16* qkv_bf = (u16*)alloc((size_t)T_ * 3 * E_ * 2);
  u16* ctx_bf = (u16*)alloc((size_t)T_ * E_ * 2);
  u16* vt_bf = (u16*)alloc((size_t)B_ * H_ * 64 * S_ * 2);
  float* invl = (float*)alloc((size_t)B_ * H_ * S_ * 4);
  u16* p_bf = (u16*)alloc((size_t)B_ * H_ * S_ * S_ * 2);
  u16* ff_bf = p_bf;                              // ff occupies lower half of P region
  float* psum = (float*)(p_bf + (size_t)T_ * F_); // W2 split-K partials, upper half
  (void)ws_size; (void)in_sizes; (void)n_in; (void)out_size; (void)rseq;

  auto cvt = [&](const float* s, u16* d, int n) {
    cvt_bf16<<<dim3((n / 4 + 255) / 256), dim3(256), 0, stream>>>(s, d, n);
  };
  cvt(gen_W, gw_bf, GEN_N * E_);

  embed_k<<<dim3(T_), dim3(256), 0, stream>>>(val_emb, ring_emb, vseq, rseq, h, x_bf);

  for (int l = 0; l < L_; ++l) {
    cvt(Wqkv + (size_t)l * 3 * E_ * E_, wqkv_l, 3 * E_ * E_);
    cvt(Wo + (size_t)l * E_ * E_, wo_l, E_ * E_);
    cvt(W1 + (size_t)l * F_ * E_, w1_l, F_ * E_);
    cvt(W2 + (size_t)l * E_ * F_, w2_l, E_ * F_);

    // QKV: 256x192 tile -> grid 16*16 = 256 exactly
    gemm_big<0, 3, 1><<<dim3(256), dim3(512), 0, stream>>>(
        x_bf, wqkv_l, bqkv + (size_t)l * 3 * E_, qkv_bf, T_, 3 * E_, E_, 16);
    vtrans_k<<<dim3(B_ * H_ * 8), dim3(256), 0, stream>>>(qkv_bf, vt_bf);
    attn_scores_k<<<dim3(B_ * H_ * 8), dim3(256), 0, stream>>>(qkv_bf, dist, dist_emb, vseq,
                                                               p_bf, invl);
    attn_pv_k<<<dim3(B_ * H_ * 4), dim3(256), 0, stream>>>(p_bf, vt_bf, invl, ctx_bf);
    gemm_bt<3><<<dim3(32 * 8), dim3(256), 0, stream>>>(
        ctx_bf, wo_l, bo + (size_t)l * E_, h, T_, E_, E_, 8);
    ln_k<<<dim3(T_), dim3(256), 0, stream>>>(h, nullptr, nullptr, nullptr,
                                             ln1_s + (size_t)l * E_, ln1_b + (size_t)l * E_,
                                             h, x_bf);
    // W1: 256x256 tile -> grid 256
    gemm_big<1, 4, 1><<<dim3(256), dim3(512), 0, stream>>>(
        x_bf, w1_l, b1 + (size_t)l * F_, ff_bf, T_, F_, E_, 16);
    // W2: 256x128 tile, split-K=2 -> grid 16*8*2 = 256; raw f32 partials
    gemm_big<2, 2, 2><<<dim3(256), dim3(512), 0, stream>>>(
        ff_bf, w2_l, nullptr, psum, T_, E_, F_, 8);
    ln_k<<<dim3(T_), dim3(256), 0, stream>>>(h, psum, psum + (size_t)T_ * E_,
                                             b2 + (size_t)l * E_,
                                             ln2_s + (size_t)l * E_, ln2_b + (size_t)l * E_,
                                             h, x_bf);
  }
  ln_k<<<dim3(T_), dim3(256), 0, stream>>>(h, nullptr, nullptr, nullptr, lnf_s, lnf_b,
                                           nullptr, x_bf);
  gemm_bt<2><<<dim3(32 * 10), dim3(256), 0, stream>>>(
      x_bf, gw_bf, gen_b, (float*)d_out, T_, GEN_N, E_, 10);
}